// Round 19
// baseline (140.757 us; speedup 1.0000x reference)
//
#include <hip/hip_runtime.h>
#include <hip/hip_bf16.h>

#define B_ 2
#define T_ 2048
#define H_ 16
#define DH_ 64
#define D_ 1024
#define KVB 128

typedef __hip_bfloat16 bf16;
typedef __attribute__((ext_vector_type(4))) float f32x4;
typedef __attribute__((ext_vector_type(8))) short s16x8;
typedef __attribute__((ext_vector_type(4))) short s16x4;
typedef __attribute__((ext_vector_type(4))) unsigned short u16x4;
typedef __attribute__((ext_vector_type(2))) unsigned int u32x2;

__device__ __forceinline__ unsigned short f2bf_bits(float f) {
  bf16 h = __float2bfloat16(f);
  return *reinterpret_cast<unsigned short*>(&h);
}

// pack two f32 -> two truncated bf16 in one v_perm_b32 (lo -> low16, hi -> high16)
__device__ __forceinline__ unsigned pk_trunc(float lo, float hi) {
  return __builtin_amdgcn_perm(__float_as_uint(hi), __float_as_uint(lo), 0x07060302u);
}

__device__ __forceinline__ void gload_lds16(const bf16* g, bf16* l) {
  __builtin_amdgcn_global_load_lds(
      (const __attribute__((address_space(1))) void*)g,
      (__attribute__((address_space(3))) void*)l, 16, 0, 0);
}

// ---------------- fused prep kernel ----------------
#define NB_CONV 4096
#define NB_TQ   3072
#define NB_TP   1024
#define NB_ROPE 256

__global__ __launch_bounds__(256)
void k_prep(const float* __restrict__ x, bf16* __restrict__ xb,
            const float* __restrict__ Wqkv, bf16* __restrict__ wqkvT,
            const float* __restrict__ Wproj, bf16* __restrict__ wprojT,
            float2* __restrict__ cs) {
  __shared__ float t[32][33];
  const int tid = threadIdx.x;
  int bid = blockIdx.x;
  if (bid < NB_CONV) {
    const int i = bid * 256 + tid;
    float4 v = reinterpret_cast<const float4*>(x)[i];
    u16x4 o;
    o[0] = f2bf_bits(v.x); o[1] = f2bf_bits(v.y);
    o[2] = f2bf_bits(v.z); o[3] = f2bf_bits(v.w);
    reinterpret_cast<u16x4*>(xb)[i] = o;
    return;
  }
  bid -= NB_CONV;
  if (bid < NB_TQ + NB_TP) {
    const float* in;
    bf16* out;
    int R, C, bx, by;
    if (bid < NB_TQ) { in = Wqkv; out = wqkvT; R = 1024; C = 3072; bx = bid % 96; by = bid / 96; }
    else { int tt = bid - NB_TQ; in = Wproj; out = wprojT; R = 1024; C = 1024; bx = tt & 31; by = tt >> 5; }
    const int c0 = bx * 32, r0 = by * 32;
    const int tx = tid & 31, ty = tid >> 5;
    #pragma unroll
    for (int i = 0; i < 32; i += 8)
      t[ty + i][tx] = in[(size_t)(r0 + ty + i) * C + (c0 + tx)];
    __syncthreads();
    #pragma unroll
    for (int i = 0; i < 32; i += 8)
      out[(size_t)(c0 + ty + i) * R + (r0 + tx)] = __float2bfloat16(t[tx][ty + i]);
    return;
  }
  bid -= NB_TQ + NB_TP;
  {
    const int i = bid * 256 + tid;
    const int tt = i >> 5, f = i & 31;
    const float NEG_L2_BASE_OVER_32 = -0.41524101186092f;  // -log2(10000)/32
    float inv = exp2f((float)f * NEG_L2_BASE_OVER_32);
    float a = (float)tt * inv;
    cs[i] = make_float2(__cosf(a), __sinf(a));
  }
}

// ---------------- GEMM: C = A[M][K] * (Bt[N][K])^T + bias ----------------
// BK=64 single-barrier dbuf + LDS slot swizzle (r15) + BN templated (r16).
// EPI=0: q pre-scaled by SCL2 (r17) so attn softmax is a bare exp2.
template <int EPI, int BN>
__global__ __launch_bounds__(256, 2)
void gemm_bt(const bf16* __restrict__ A, const bf16* __restrict__ Bt,
             const float* __restrict__ bias, float* __restrict__ outF,
             bf16* __restrict__ qb, bf16* __restrict__ kb, bf16* __restrict__ vb,
             const float2* __restrict__ cs, int M, int N, int K) {
  constexpr int NJ = BN / 32;
  constexpr int WN = BN / 2;
  __shared__ __align__(16) bf16 As[2][128 * 64];
  __shared__ __align__(16) bf16 Bs[2][BN * 64];
  const int tid = threadIdx.x;
  const int w = tid >> 6, l = tid & 63;
  const int wr = w >> 1, wc = w & 1;
  const int nwg = gridDim.x;
  int bid = blockIdx.x;
  bid = (bid & 7) * (nwg >> 3) + (bid >> 3);
  const int nxb = N / BN;
  const int m0 = (bid / nxb) * 128, n0 = (bid % nxb) * BN;
  const int l15 = l & 15, l4 = l >> 4;
  const int srow = w * 8 + (l >> 3);
  const int sslot = (l & 7) ^ ((l >> 3) & 7);
  const int rsw = l15 & 7;
  f32x4 acc[4][NJ] = {};

  auto stage = [&](int k0, int b) {
    #pragma unroll
    for (int p = 0; p < 4; ++p) {
      const int row = p * 32 + srow;
      gload_lds16(A + (size_t)(m0 + row) * K + k0 + sslot * 8, &As[b][(p * 32 + w * 8) * 64] + l * 8);
    }
    #pragma unroll
    for (int p = 0; p < BN / 32; ++p) {
      const int row = p * 32 + srow;
      gload_lds16(Bt + (size_t)(n0 + row) * K + k0 + sslot * 8, &Bs[b][(p * 32 + w * 8) * 64] + l * 8);
    }
  };

  const int nt = K >> 6;
  stage(0, 0);
  __syncthreads();
  int bufi = 0;
  for (int t = 0; t < nt; ++t) {
    if (t + 1 < nt) stage((t + 1) << 6, bufi ^ 1);
    s16x8 af[4][2], bfr[NJ][2];
    #pragma unroll
    for (int i = 0; i < 4; ++i)
      #pragma unroll
      for (int h = 0; h < 2; ++h)
        af[i][h] = *(const s16x8*)(&As[bufi][(wr * 64 + i * 16 + l15) * 64] + (((h * 4 + l4) ^ rsw) * 8));
    #pragma unroll
    for (int j = 0; j < NJ; ++j)
      #pragma unroll
      for (int h = 0; h < 2; ++h)
        bfr[j][h] = *(const s16x8*)(&Bs[bufi][(wc * WN + j * 16 + l15) * 64] + (((h * 4 + l4) ^ rsw) * 8));
    #pragma unroll
    for (int i = 0; i < 4; ++i)
      #pragma unroll
      for (int j = 0; j < NJ; ++j) {
        acc[i][j] = __builtin_amdgcn_mfma_f32_16x16x32_bf16(af[i][0], bfr[j][0], acc[i][j], 0, 0, 0);
        acc[i][j] = __builtin_amdgcn_mfma_f32_16x16x32_bf16(af[i][1], bfr[j][1], acc[i][j], 0, 0, 0);
      }
    __syncthreads();
    bufi ^= 1;
  }

  if (EPI == 1) {
    #pragma unroll
    for (int i = 0; i < 4; ++i)
      #pragma unroll
      for (int j = 0; j < NJ; ++j) {
        const int ng = n0 + wc * WN + j * 16 + l15;
        const float bv = bias[ng];
        #pragma unroll
        for (int jj = 0; jj < 4; ++jj) {
          const int mg = m0 + wr * 64 + i * 16 + l4 * 4 + jj;
          outF[(size_t)mg * N + ng] = acc[i][j][jj] + bv;
        }
      }
  } else {
    const float SCL2 = 0.125f * 1.44269504089f;
    #pragma unroll
    for (int i = 0; i < 4; ++i)
      #pragma unroll
      for (int j = 0; j < NJ; ++j) {
        const int ng = n0 + wc * WN + j * 16 + l15;
        const int part = ng >> 10;
        const int d = ng & 63;
        const int h = (ng >> 6) & 15;
        const float bv = bias[ng];
        if (part == 2) {
          const int mg0 = m0 + wr * 64 + i * 16 + l4 * 4;
          const int t0 = mg0 & (T_ - 1);
          const int b = mg0 >> 11;
          u16x4 ov;
          #pragma unroll
          for (int jj = 0; jj < 4; ++jj) ov[jj] = f2bf_bits(acc[i][j][jj] + bv);
          *(u16x4*)(vb + ((size_t)(b * H_ + h) * DH_ + d) * T_ + t0) = ov;
        } else {
          #pragma unroll
          for (int jj = 0; jj < 4; ++jj) {
            const int mg = m0 + wr * 64 + i * 16 + l4 * 4 + jj;
            const int t = mg & (T_ - 1);
            const int b = mg >> 11;
            float v = acc[i][j][jj] + bv;
            float pp = __shfl_xor(v, 1);
            float2 csv = cs[t * 32 + (d >> 1)];
            float o = (d & 1) ? (v * csv.x + pp * csv.y) : (v * csv.x - pp * csv.y);
            if (part == 0) o *= SCL2;
            bf16* dst = (part == 0) ? qb : kb;
            dst[(size_t)((b * H_ + h) * T_ + t) * DH_ + d] = __float2bfloat16(o);
          }
        }
      }
  }
}

// ---------------- flash attention v7: 32-row-strip pairs, 1024 blocks, 3 blocks/CU ----------------
// Pair {pi, 63-pi} of 32-row strips; waves 0-1 own A's two 16-row tiles, waves 2-3 own B's.
// Per-block compute uniform (~16.25 active wave-tiles); nkt variance (9..16) absorbed by
// 256 backfill blocks. Single O/ls state per wave -> ~75 VGPR. 48KB LDS -> 3 blocks/CU.
__global__ __launch_bounds__(256, 2)
void attn_fwd(const bf16* __restrict__ qb, const bf16* __restrict__ kb,
              const bf16* __restrict__ vtb, bf16* __restrict__ y) {
  __shared__ __align__(16) bf16 Ks[2][KVB * 64];   // 32 KB
  __shared__ __align__(16) bf16 Vs[64 * KVB];      // 16 KB

  const int tid = threadIdx.x;
  const int w = tid >> 6, l = tid & 63;
  const int l15 = l & 15, l4 = l >> 4;
  const int pi = blockIdx.x & 31;                  // heavy (low pi) dispatch-early
  const int bh = blockIdx.x >> 5;
  const int nkt = (64 - pi + 3) >> 2;              // ceil((64-pi)/4): 16..9
  // waves 0,1 -> A strip pi; waves 2,3 -> B strip 63-pi
  const int wq = (w < 2) ? (pi * 32 + w * 16) : ((63 - pi) * 32 + (w - 2) * 16);

  const bf16* qp = qb + (size_t)bh * T_ * DH_;
  const bf16* kp = kb + (size_t)bh * T_ * DH_;
  const bf16* vtp = vtb + (size_t)bh * DH_ * T_;

  const s16x8 q0 = *(const s16x8*)(qp + (size_t)(wq + l15) * DH_ + l4 * 8);
  const s16x8 q1 = *(const s16x8*)(qp + (size_t)(wq + l15) * DH_ + l4 * 8 + 32);

  const int krow_ = tid >> 3, kslot_ = tid & 7;
  const int vrow_ = tid >> 4, vslot_ = tid & 15;

  auto stageK = [&](int kt, int b) {
    const bf16* ksrc = kp + (size_t)kt * KVB * DH_;
    #pragma unroll
    for (int p = 0; p < 4; ++p) {
      const int r = p * 32 + krow_;
      gload_lds16(ksrc + (size_t)r * DH_ + ((kslot_ ^ (r & 7)) * 8),
                  &Ks[b][r * 64 + kslot_ * 8]);
    }
  };
  auto stageV = [&](int kt) {
    #pragma unroll
    for (int p = 0; p < 4; ++p) {
      const int r = p * 16 + vrow_;
      gload_lds16(vtp + (size_t)r * T_ + kt * KVB + ((vslot_ ^ (r & 15)) * 8),
                  &Vs[r * KVB + vslot_ * 8]);
    }
  };

  f32x4 O[4] = {};
  float ls = 0.0f;

  stageK(0, 0);
  stageV(0);
  __syncthreads();

  int buf = 0;
  for (int kt = 0; kt < nkt; ++kt) {
    if (kt + 1 < nkt) stageK(kt + 1, buf ^ 1);   // hides under QK + softmax
    const int k0 = kt * KVB;
    const bool act = (k0 <= wq + 15);            // wave-uniform

    f32x4 s[8];
    const int rsw = l15 & 7;
    if (act) {
      __builtin_amdgcn_s_setprio(1);
      #pragma unroll
      for (int ks = 0; ks < 8; ++ks) {
        const bf16* krow = &Ks[buf][(ks * 16 + l15) * 64];
        const s16x8 kf0 = *(const s16x8*)(krow + ((l4 ^ rsw) * 8));
        const s16x8 kf1 = *(const s16x8*)(krow + (((4 + l4) ^ rsw) * 8));
        f32x4 t = {};
        t = __builtin_amdgcn_mfma_f32_16x16x32_bf16(kf0, q0, t, 0, 0, 0);
        t = __builtin_amdgcn_mfma_f32_16x16x32_bf16(kf1, q1, t, 0, 0, 0);
        s[ks] = t;
      }
      __builtin_amdgcn_s_setprio(0);

      // fixed-m softmax (scale pre-folded into q)
      if (k0 + KVB - 1 > wq) {
        const int q = wq + l15;
        #pragma unroll
        for (int ks = 0; ks < 8; ++ks)
          #pragma unroll
          for (int j = 0; j < 4; ++j)
            if (k0 + ks * 16 + l4 * 4 + j > q) s[ks][j] = -1e30f;
      }
      float ts = 0.0f;
      #pragma unroll
      for (int ks = 0; ks < 8; ++ks) {
        f32x4 pv;
        #pragma unroll
        for (int j = 0; j < 4; ++j) pv[j] = exp2f(s[ks][j]);
        s[ks] = pv;
        ts += (pv[0] + pv[1]) + (pv[2] + pv[3]);
      }
      ts += __shfl_xor(ts, 16);
      ts += __shfl_xor(ts, 32);
      ls += ts;
    }

    __syncthreads();   // A: V(kt) staged by all; K(kt+1) drained here

    if (act) {
      __builtin_amdgcn_s_setprio(1);
      #pragma unroll
      for (int ks = 0; ks < 8; ++ks) {
        u32x2 t2;
        t2.x = pk_trunc(s[ks][0], s[ks][1]);
        t2.y = pk_trunc(s[ks][2], s[ks][3]);
        const s16x4 pb = __builtin_bit_cast(s16x4, t2);
        const int slotb = ks * 2 + (l4 >> 1);
        const int inoff = (l4 & 1) * 8;
        #pragma unroll
        for (int dt = 0; dt < 4; ++dt) {
          const int d = dt * 16 + l15;
          const char* vrow = (const char*)&Vs[d * KVB];
          u16x4 vf = *(const u16x4*)(vrow + ((slotb ^ (d & 15)) * 16 + inoff));
          O[dt] = __builtin_amdgcn_mfma_f32_16x16x16bf16_1k(*(const s16x4*)&vf, pb, O[dt], 0, 0, 0);
        }
      }
      __builtin_amdgcn_s_setprio(0);
    }

    __syncthreads();   // B: all reads of Vs / Ks[buf] complete
    if (kt + 1 < nkt) stageV(kt + 1);
    buf ^= 1;
  }

  const int b = bh >> 4, h = bh & 15;
  const float inv = 1.0f / ls;
  bf16* yr = y + ((size_t)(b * T_ + wq + l15)) * D_ + h * DH_;
  #pragma unroll
  for (int dt = 0; dt < 4; ++dt) {
    u32x2 ov;
    ov.x = pk_trunc(O[dt][0] * inv, O[dt][1] * inv);
    ov.y = pk_trunc(O[dt][2] * inv, O[dt][3] * inv);
    *(u32x2*)(yr + dt * 16 + l4 * 4) = ov;
  }
}

// ---------------- launcher ----------------

extern "C" void kernel_launch(void* const* d_in, const int* in_sizes, int n_in,
                              void* d_out, int out_size, void* d_ws, size_t ws_size,
                              hipStream_t stream) {
  (void)in_sizes; (void)n_in; (void)out_size; (void)ws_size;
  const float* x     = (const float*)d_in[0];
  const float* Wqkv  = (const float*)d_in[1];
  const float* bqkv  = (const float*)d_in[2];
  const float* Wproj = (const float*)d_in[3];
  const float* bproj = (const float*)d_in[4];
  float* outF = (float*)d_out;

  const size_t NTOK = (size_t)B_ * T_;
  const size_t NELM = NTOK * D_;

  char* p = (char*)d_ws;
  bf16* xb     = (bf16*)p; p += NELM * 2;
  bf16* wqkvT  = (bf16*)p; p += (size_t)3 * D_ * D_ * 2;
  bf16* wprojT = (bf16*)p; p += (size_t)D_ * D_ * 2;
  bf16* qbuf   = (bf16*)p; p += NELM * 2;                 // [B*H][T][DH]  (q pre-scaled)
  bf16* kbuf   = (bf16*)p; p += NELM * 2;                 // [B*H][T][DH]
  bf16* vtbuf  = (bf16*)p; p += NELM * 2;                 // [B*H][DH][T]
  bf16* ybuf   = (bf16*)p; p += NELM * 2;                 // [B][T][D]
  float2* cs   = (float2*)p; p += (size_t)T_ * 32 * sizeof(float2);

  k_prep<<<dim3(NB_CONV + NB_TQ + NB_TP + NB_ROPE), dim3(256), 0, stream>>>(
      x, xb, Wqkv, wqkvT, Wproj, wprojT, cs);

  gemm_bt<0, 192><<<dim3(512), dim3(256), 0, stream>>>(
      xb, wqkvT, bqkv, nullptr, qbuf, kbuf, vtbuf, cs, (int)NTOK, 3 * D_, D_);

  attn_fwd<<<dim3(1024), dim3(256), 0, stream>>>(qbuf, kbuf, vtbuf, ybuf);

  gemm_bt<1, 128><<<dim3(8 * 32), dim3(256), 0, stream>>>(
      ybuf, wprojT, bproj, outF, nullptr, nullptr, nullptr, cs, (int)NTOK, D_, D_);
}

// Round 20
// 122.256 us; speedup vs baseline: 1.1513x; 1.1513x over previous
//
#include <hip/hip_runtime.h>
#include <hip/hip_bf16.h>

#define B_ 2
#define T_ 2048
#define H_ 16
#define DH_ 64
#define D_ 1024
#define KVB 128

typedef __hip_bfloat16 bf16;
typedef __attribute__((ext_vector_type(4))) float f32x4;
typedef __attribute__((ext_vector_type(8))) short s16x8;
typedef __attribute__((ext_vector_type(4))) short s16x4;
typedef __attribute__((ext_vector_type(4))) unsigned short u16x4;
typedef __attribute__((ext_vector_type(2))) unsigned int u32x2;

__device__ __forceinline__ unsigned short f2bf_bits(float f) {
  bf16 h = __float2bfloat16(f);
  return *reinterpret_cast<unsigned short*>(&h);
}

// pack two f32 -> two truncated bf16 in one v_perm_b32 (lo -> low16, hi -> high16)
__device__ __forceinline__ unsigned pk_trunc(float lo, float hi) {
  return __builtin_amdgcn_perm(__float_as_uint(hi), __float_as_uint(lo), 0x07060302u);
}

__device__ __forceinline__ void gload_lds16(const bf16* g, bf16* l) {
  __builtin_amdgcn_global_load_lds(
      (const __attribute__((address_space(1))) void*)g,
      (__attribute__((address_space(3))) void*)l, 16, 0, 0);
}

// ---------------- fused prep kernel ----------------
#define NB_CONV 4096
#define NB_TQ   3072
#define NB_TP   1024
#define NB_ROPE 256

__global__ __launch_bounds__(256)
void k_prep(const float* __restrict__ x, bf16* __restrict__ xb,
            const float* __restrict__ Wqkv, bf16* __restrict__ wqkvT,
            const float* __restrict__ Wproj, bf16* __restrict__ wprojT,
            float2* __restrict__ cs) {
  __shared__ float t[32][33];
  const int tid = threadIdx.x;
  int bid = blockIdx.x;
  if (bid < NB_CONV) {
    const int i = bid * 256 + tid;
    float4 v = reinterpret_cast<const float4*>(x)[i];
    u16x4 o;
    o[0] = f2bf_bits(v.x); o[1] = f2bf_bits(v.y);
    o[2] = f2bf_bits(v.z); o[3] = f2bf_bits(v.w);
    reinterpret_cast<u16x4*>(xb)[i] = o;
    return;
  }
  bid -= NB_CONV;
  if (bid < NB_TQ + NB_TP) {
    const float* in;
    bf16* out;
    int R, C, bx, by;
    if (bid < NB_TQ) { in = Wqkv; out = wqkvT; R = 1024; C = 3072; bx = bid % 96; by = bid / 96; }
    else { int tt = bid - NB_TQ; in = Wproj; out = wprojT; R = 1024; C = 1024; bx = tt & 31; by = tt >> 5; }
    const int c0 = bx * 32, r0 = by * 32;
    const int tx = tid & 31, ty = tid >> 5;
    #pragma unroll
    for (int i = 0; i < 32; i += 8)
      t[ty + i][tx] = in[(size_t)(r0 + ty + i) * C + (c0 + tx)];
    __syncthreads();
    #pragma unroll
    for (int i = 0; i < 32; i += 8)
      out[(size_t)(c0 + ty + i) * R + (r0 + tx)] = __float2bfloat16(t[tx][ty + i]);
    return;
  }
  bid -= NB_TQ + NB_TP;
  {
    const int i = bid * 256 + tid;
    const int tt = i >> 5, f = i & 31;
    const float NEG_L2_BASE_OVER_32 = -0.41524101186092f;  // -log2(10000)/32
    float inv = exp2f((float)f * NEG_L2_BASE_OVER_32);
    float a = (float)tt * inv;
    cs[i] = make_float2(__cosf(a), __sinf(a));
  }
}

// ---------------- GEMM: C = A[M][K] * (Bt[N][K])^T + bias ----------------
// BK=64 single-barrier dbuf + LDS slot swizzle (r15) + BN templated (r16).
// EPI=0: q pre-scaled by SCL2 (r17) so attn softmax is a bare exp2.
template <int EPI, int BN>
__global__ __launch_bounds__(256, 2)
void gemm_bt(const bf16* __restrict__ A, const bf16* __restrict__ Bt,
             const float* __restrict__ bias, float* __restrict__ outF,
             bf16* __restrict__ qb, bf16* __restrict__ kb, bf16* __restrict__ vb,
             const float2* __restrict__ cs, int M, int N, int K) {
  constexpr int NJ = BN / 32;
  constexpr int WN = BN / 2;
  __shared__ __align__(16) bf16 As[2][128 * 64];
  __shared__ __align__(16) bf16 Bs[2][BN * 64];
  const int tid = threadIdx.x;
  const int w = tid >> 6, l = tid & 63;
  const int wr = w >> 1, wc = w & 1;
  const int nwg = gridDim.x;
  int bid = blockIdx.x;
  bid = (bid & 7) * (nwg >> 3) + (bid >> 3);
  const int nxb = N / BN;
  const int m0 = (bid / nxb) * 128, n0 = (bid % nxb) * BN;
  const int l15 = l & 15, l4 = l >> 4;
  const int srow = w * 8 + (l >> 3);
  const int sslot = (l & 7) ^ ((l >> 3) & 7);
  const int rsw = l15 & 7;
  f32x4 acc[4][NJ] = {};

  auto stage = [&](int k0, int b) {
    #pragma unroll
    for (int p = 0; p < 4; ++p) {
      const int row = p * 32 + srow;
      gload_lds16(A + (size_t)(m0 + row) * K + k0 + sslot * 8, &As[b][(p * 32 + w * 8) * 64] + l * 8);
    }
    #pragma unroll
    for (int p = 0; p < BN / 32; ++p) {
      const int row = p * 32 + srow;
      gload_lds16(Bt + (size_t)(n0 + row) * K + k0 + sslot * 8, &Bs[b][(p * 32 + w * 8) * 64] + l * 8);
    }
  };

  const int nt = K >> 6;
  stage(0, 0);
  __syncthreads();
  int bufi = 0;
  for (int t = 0; t < nt; ++t) {
    if (t + 1 < nt) stage((t + 1) << 6, bufi ^ 1);
    s16x8 af[4][2], bfr[NJ][2];
    #pragma unroll
    for (int i = 0; i < 4; ++i)
      #pragma unroll
      for (int h = 0; h < 2; ++h)
        af[i][h] = *(const s16x8*)(&As[bufi][(wr * 64 + i * 16 + l15) * 64] + (((h * 4 + l4) ^ rsw) * 8));
    #pragma unroll
    for (int j = 0; j < NJ; ++j)
      #pragma unroll
      for (int h = 0; h < 2; ++h)
        bfr[j][h] = *(const s16x8*)(&Bs[bufi][(wc * WN + j * 16 + l15) * 64] + (((h * 4 + l4) ^ rsw) * 8));
    #pragma unroll
    for (int i = 0; i < 4; ++i)
      #pragma unroll
      for (int j = 0; j < NJ; ++j) {
        acc[i][j] = __builtin_amdgcn_mfma_f32_16x16x32_bf16(af[i][0], bfr[j][0], acc[i][j], 0, 0, 0);
        acc[i][j] = __builtin_amdgcn_mfma_f32_16x16x32_bf16(af[i][1], bfr[j][1], acc[i][j], 0, 0, 0);
      }
    __syncthreads();
    bufi ^= 1;
  }

  if (EPI == 1) {
    #pragma unroll
    for (int i = 0; i < 4; ++i)
      #pragma unroll
      for (int j = 0; j < NJ; ++j) {
        const int ng = n0 + wc * WN + j * 16 + l15;
        const float bv = bias[ng];
        #pragma unroll
        for (int jj = 0; jj < 4; ++jj) {
          const int mg = m0 + wr * 64 + i * 16 + l4 * 4 + jj;
          outF[(size_t)mg * N + ng] = acc[i][j][jj] + bv;
        }
      }
  } else {
    const float SCL2 = 0.125f * 1.44269504089f;
    #pragma unroll
    for (int i = 0; i < 4; ++i)
      #pragma unroll
      for (int j = 0; j < NJ; ++j) {
        const int ng = n0 + wc * WN + j * 16 + l15;
        const int part = ng >> 10;
        const int d = ng & 63;
        const int h = (ng >> 6) & 15;
        const float bv = bias[ng];
        if (part == 2) {
          const int mg0 = m0 + wr * 64 + i * 16 + l4 * 4;
          const int t0 = mg0 & (T_ - 1);
          const int b = mg0 >> 11;
          u16x4 ov;
          #pragma unroll
          for (int jj = 0; jj < 4; ++jj) ov[jj] = f2bf_bits(acc[i][j][jj] + bv);
          *(u16x4*)(vb + ((size_t)(b * H_ + h) * DH_ + d) * T_ + t0) = ov;
        } else {
          #pragma unroll
          for (int jj = 0; jj < 4; ++jj) {
            const int mg = m0 + wr * 64 + i * 16 + l4 * 4 + jj;
            const int t = mg & (T_ - 1);
            const int b = mg >> 11;
            float v = acc[i][j][jj] + bv;
            float pp = __shfl_xor(v, 1);
            float2 csv = cs[t * 32 + (d >> 1)];
            float o = (d & 1) ? (v * csv.x + pp * csv.y) : (v * csv.x - pp * csv.y);
            if (part == 0) o *= SCL2;
            bf16* dst = (part == 0) ? qb : kb;
            dst[(size_t)((b * H_ + h) * T_ + t) * DH_ + d] = __float2bfloat16(o);
          }
        }
      }
  }
}

// ---------------- flash attention v5g (round-18 best: fixed-m + folded scale + perm-pack) ----------------
// r19's 3-block/CU strip pairing REVERTED: conflict sentinel fired (4.45M, = r11) and
// MfmaUtil halved. The 4-wave uniform-pair 2-block/CU schedule is the local optimum.
__global__ __launch_bounds__(256, 2)
void attn_fwd(const bf16* __restrict__ qb, const bf16* __restrict__ kb,
              const bf16* __restrict__ vtb, bf16* __restrict__ y) {
  __shared__ __align__(16) bf16 Ks[2][KVB * 64];   // 32 KB
  __shared__ __align__(16) bf16 Vs[64 * KVB];      // 16 KB

  const int tid = threadIdx.x;
  const int w = tid >> 6, l = tid & 63;
  const int l15 = l & 15, l4 = l >> 4;
  const int pi = blockIdx.x & 15;
  const int bh = blockIdx.x >> 4;
  const int nkt = (33 - pi) >> 1;
  const int wqA = pi * 64 + w * 16;
  const int wqB = (31 - pi) * 64 + w * 16;

  const bf16* qp = qb + (size_t)bh * T_ * DH_;
  const bf16* kp = kb + (size_t)bh * T_ * DH_;
  const bf16* vtp = vtb + (size_t)bh * DH_ * T_;

  const s16x8 qA0 = *(const s16x8*)(qp + (size_t)(wqA + l15) * DH_ + l4 * 8);
  const s16x8 qA1 = *(const s16x8*)(qp + (size_t)(wqA + l15) * DH_ + l4 * 8 + 32);
  const s16x8 qB0 = *(const s16x8*)(qp + (size_t)(wqB + l15) * DH_ + l4 * 8);
  const s16x8 qB1 = *(const s16x8*)(qp + (size_t)(wqB + l15) * DH_ + l4 * 8 + 32);

  const int krow_ = tid >> 3, kslot_ = tid & 7;
  const int vrow_ = tid >> 4, vslot_ = tid & 15;

  auto stageK = [&](int kt, int b) {
    const bf16* ksrc = kp + (size_t)kt * KVB * DH_;
    #pragma unroll
    for (int p = 0; p < 4; ++p) {
      const int r = p * 32 + krow_;
      gload_lds16(ksrc + (size_t)r * DH_ + ((kslot_ ^ (r & 7)) * 8),
                  &Ks[b][r * 64 + kslot_ * 8]);
    }
  };
  auto stageV = [&](int kt) {
    #pragma unroll
    for (int p = 0; p < 4; ++p) {
      const int r = p * 16 + vrow_;
      gload_lds16(vtp + (size_t)r * T_ + kt * KVB + ((vslot_ ^ (r & 15)) * 8),
                  &Vs[r * KVB + vslot_ * 8]);
    }
  };

  f32x4 OA[4] = {}, OB[4] = {};
  float lsA = 0.0f, lsB = 0.0f;

  stageK(0, 0);
  stageV(0);
  __syncthreads();

  int buf = 0;
  for (int kt = 0; kt < nkt; ++kt) {
    if (kt + 1 < nkt) stageK(kt + 1, buf ^ 1);
    const int k0 = kt * KVB;
    const bool actA = (k0 <= wqA + 15);

    f32x4 sA[8], sB[8];
    const int rsw = l15 & 7;
    __builtin_amdgcn_s_setprio(1);
    #pragma unroll
    for (int ks = 0; ks < 8; ++ks) {
      const bf16* krow = &Ks[buf][(ks * 16 + l15) * 64];
      const s16x8 kf0 = *(const s16x8*)(krow + ((l4 ^ rsw) * 8));
      const s16x8 kf1 = *(const s16x8*)(krow + (((4 + l4) ^ rsw) * 8));
      f32x4 t = {};
      t = __builtin_amdgcn_mfma_f32_16x16x32_bf16(kf0, qB0, t, 0, 0, 0);
      t = __builtin_amdgcn_mfma_f32_16x16x32_bf16(kf1, qB1, t, 0, 0, 0);
      sB[ks] = t;
      if (actA) {
        f32x4 u = {};
        u = __builtin_amdgcn_mfma_f32_16x16x32_bf16(kf0, qA0, u, 0, 0, 0);
        u = __builtin_amdgcn_mfma_f32_16x16x32_bf16(kf1, qA1, u, 0, 0, 0);
        sA[ks] = u;
      }
    }
    __builtin_amdgcn_s_setprio(0);

    auto softmax = [&](f32x4 (&s)[8], float& lsum, int wq) {
      if (k0 + KVB - 1 > wq) {
        const int q = wq + l15;
        #pragma unroll
        for (int ks = 0; ks < 8; ++ks)
          #pragma unroll
          for (int j = 0; j < 4; ++j)
            if (k0 + ks * 16 + l4 * 4 + j > q) s[ks][j] = -1e30f;
      }
      float ts = 0.0f;
      #pragma unroll
      for (int ks = 0; ks < 8; ++ks) {
        f32x4 pv;
        #pragma unroll
        for (int j = 0; j < 4; ++j) pv[j] = exp2f(s[ks][j]);   // scale pre-folded into q
        s[ks] = pv;
        ts += (pv[0] + pv[1]) + (pv[2] + pv[3]);
      }
      ts += __shfl_xor(ts, 16);
      ts += __shfl_xor(ts, 32);
      lsum += ts;
    };
    softmax(sB, lsB, wqB);
    if (actA) softmax(sA, lsA, wqA);

    __syncthreads();   // A: V(kt) staged by all; K(kt+1) drained here

    __builtin_amdgcn_s_setprio(1);
    #pragma unroll
    for (int ks = 0; ks < 8; ++ks) {
      s16x4 pbB = {}, pbA = {};
      {
        u32x2 t2;
        t2.x = pk_trunc(sB[ks][0], sB[ks][1]);
        t2.y = pk_trunc(sB[ks][2], sB[ks][3]);
        pbB = __builtin_bit_cast(s16x4, t2);
      }
      if (actA) {
        u32x2 t2;
        t2.x = pk_trunc(sA[ks][0], sA[ks][1]);
        t2.y = pk_trunc(sA[ks][2], sA[ks][3]);
        pbA = __builtin_bit_cast(s16x4, t2);
      }
      const int slotb = ks * 2 + (l4 >> 1);
      const int inoff = (l4 & 1) * 8;
      #pragma unroll
      for (int dt = 0; dt < 4; ++dt) {
        const int d = dt * 16 + l15;
        const char* vrow = (const char*)&Vs[d * KVB];
        u16x4 vf = *(const u16x4*)(vrow + ((slotb ^ (d & 15)) * 16 + inoff));
        OB[dt] = __builtin_amdgcn_mfma_f32_16x16x16bf16_1k(*(const s16x4*)&vf, pbB, OB[dt], 0, 0, 0);
        if (actA)
          OA[dt] = __builtin_amdgcn_mfma_f32_16x16x16bf16_1k(*(const s16x4*)&vf, pbA, OA[dt], 0, 0, 0);
      }
    }
    __builtin_amdgcn_s_setprio(0);

    __syncthreads();   // B: all reads of Vs / Ks[buf] complete
    if (kt + 1 < nkt) stageV(kt + 1);
    buf ^= 1;
  }

  const int b = bh >> 4, h = bh & 15;
  auto writeO = [&](f32x4 (&O)[4], float lsum, int wq) {
    const float inv = 1.0f / lsum;
    bf16* yr = y + ((size_t)(b * T_ + wq + l15)) * D_ + h * DH_;
    #pragma unroll
    for (int dt = 0; dt < 4; ++dt) {
      u32x2 ov;
      ov.x = pk_trunc(O[dt][0] * inv, O[dt][1] * inv);
      ov.y = pk_trunc(O[dt][2] * inv, O[dt][3] * inv);
      *(u32x2*)(yr + dt * 16 + l4 * 4) = ov;
    }
  };
  writeO(OA, lsA, wqA);
  writeO(OB, lsB, wqB);
}

// ---------------- launcher ----------------

extern "C" void kernel_launch(void* const* d_in, const int* in_sizes, int n_in,
                              void* d_out, int out_size, void* d_ws, size_t ws_size,
                              hipStream_t stream) {
  (void)in_sizes; (void)n_in; (void)out_size; (void)ws_size;
  const float* x     = (const float*)d_in[0];
  const float* Wqkv  = (const float*)d_in[1];
  const float* bqkv  = (const float*)d_in[2];
  const float* Wproj = (const float*)d_in[3];
  const float* bproj = (const float*)d_in[4];
  float* outF = (float*)d_out;

  const size_t NTOK = (size_t)B_ * T_;
  const size_t NELM = NTOK * D_;

  char* p = (char*)d_ws;
  bf16* xb     = (bf16*)p; p += NELM * 2;
  bf16* wqkvT  = (bf16*)p; p += (size_t)3 * D_ * D_ * 2;
  bf16* wprojT = (bf16*)p; p += (size_t)D_ * D_ * 2;
  bf16* qbuf   = (bf16*)p; p += NELM * 2;                 // [B*H][T][DH]  (q pre-scaled)
  bf16* kbuf   = (bf16*)p; p += NELM * 2;                 // [B*H][T][DH]
  bf16* vtbuf  = (bf16*)p; p += NELM * 2;                 // [B*H][DH][T]
  bf16* ybuf   = (bf16*)p; p += NELM * 2;                 // [B][T][D]
  float2* cs   = (float2*)p; p += (size_t)T_ * 32 * sizeof(float2);

  k_prep<<<dim3(NB_CONV + NB_TQ + NB_TP + NB_ROPE), dim3(256), 0, stream>>>(
      x, xb, Wqkv, wqkvT, Wproj, wprojT, cs);

  gemm_bt<0, 192><<<dim3(512), dim3(256), 0, stream>>>(
      xb, wqkvT, bqkv, nullptr, qbuf, kbuf, vtbuf, cs, (int)NTOK, 3 * D_, D_);

  attn_fwd<<<dim3(512), dim3(256), 0, stream>>>(qbuf, kbuf, vtbuf, ybuf);

  gemm_bt<1, 128><<<dim3(8 * 32), dim3(256), 0, stream>>>(
      ybuf, wprojT, bproj, outF, nullptr, nullptr, nullptr, cs, (int)NTOK, D_, D_);
}

// Round 21
// 118.263 us; speedup vs baseline: 1.1902x; 1.0338x over previous
//
#include <hip/hip_runtime.h>
#include <hip/hip_bf16.h>

#define B_ 2
#define T_ 2048
#define H_ 16
#define DH_ 64
#define D_ 1024
#define KVB 128

typedef __hip_bfloat16 bf16;
typedef __attribute__((ext_vector_type(4))) float f32x4;
typedef __attribute__((ext_vector_type(8))) short s16x8;
typedef __attribute__((ext_vector_type(4))) short s16x4;
typedef __attribute__((ext_vector_type(4))) unsigned short u16x4;
typedef __attribute__((ext_vector_type(2))) unsigned int u32x2;

__device__ __forceinline__ unsigned short f2bf_bits(float f) {
  bf16 h = __float2bfloat16(f);
  return *reinterpret_cast<unsigned short*>(&h);
}

// pack two f32 -> two truncated bf16 in one v_perm_b32 (lo -> low16, hi -> high16)
__device__ __forceinline__ unsigned pk_trunc(float lo, float hi) {
  return __builtin_amdgcn_perm(__float_as_uint(hi), __float_as_uint(lo), 0x07060302u);
}

__device__ __forceinline__ void gload_lds16(const bf16* g, bf16* l) {
  __builtin_amdgcn_global_load_lds(
      (const __attribute__((address_space(1))) void*)g,
      (__attribute__((address_space(3))) void*)l, 16, 0, 0);
}

// ---------------- fused prep kernel ----------------
#define NB_CONV 4096
#define NB_TQ   3072
#define NB_TP   1024
#define NB_ROPE 256

__global__ __launch_bounds__(256)
void k_prep(const float* __restrict__ x, bf16* __restrict__ xb,
            const float* __restrict__ Wqkv, bf16* __restrict__ wqkvT,
            const float* __restrict__ Wproj, bf16* __restrict__ wprojT,
            float2* __restrict__ cs) {
  __shared__ float t[32][33];
  const int tid = threadIdx.x;
  int bid = blockIdx.x;
  if (bid < NB_CONV) {
    const int i = bid * 256 + tid;
    float4 v = reinterpret_cast<const float4*>(x)[i];
    u16x4 o;
    o[0] = f2bf_bits(v.x); o[1] = f2bf_bits(v.y);
    o[2] = f2bf_bits(v.z); o[3] = f2bf_bits(v.w);
    reinterpret_cast<u16x4*>(xb)[i] = o;
    return;
  }
  bid -= NB_CONV;
  if (bid < NB_TQ + NB_TP) {
    const float* in;
    bf16* out;
    int R, C, bx, by;
    if (bid < NB_TQ) { in = Wqkv; out = wqkvT; R = 1024; C = 3072; bx = bid % 96; by = bid / 96; }
    else { int tt = bid - NB_TQ; in = Wproj; out = wprojT; R = 1024; C = 1024; bx = tt & 31; by = tt >> 5; }
    const int c0 = bx * 32, r0 = by * 32;
    const int tx = tid & 31, ty = tid >> 5;
    #pragma unroll
    for (int i = 0; i < 32; i += 8)
      t[ty + i][tx] = in[(size_t)(r0 + ty + i) * C + (c0 + tx)];
    __syncthreads();
    #pragma unroll
    for (int i = 0; i < 32; i += 8)
      out[(size_t)(c0 + ty + i) * R + (r0 + tx)] = __float2bfloat16(t[tx][ty + i]);
    return;
  }
  bid -= NB_TQ + NB_TP;
  {
    const int i = bid * 256 + tid;
    const int tt = i >> 5, f = i & 31;
    const float NEG_L2_BASE_OVER_32 = -0.41524101186092f;  // -log2(10000)/32
    float inv = exp2f((float)f * NEG_L2_BASE_OVER_32);
    float a = (float)tt * inv;
    cs[i] = make_float2(__cosf(a), __sinf(a));
  }
}

// ---------------- GEMM: C = A[M][K] * (Bt[N][K])^T + bias ----------------
// BK=64 single-barrier dbuf + LDS slot swizzle (r15) + BN templated (r16).
// EPI=0: q pre-scaled by SCL2 (r17) so attn softmax is a bare exp2.
template <int EPI, int BN>
__global__ __launch_bounds__(256, 2)
void gemm_bt(const bf16* __restrict__ A, const bf16* __restrict__ Bt,
             const float* __restrict__ bias, float* __restrict__ outF,
             bf16* __restrict__ qb, bf16* __restrict__ kb, bf16* __restrict__ vb,
             const float2* __restrict__ cs, int M, int N, int K) {
  constexpr int NJ = BN / 32;
  constexpr int WN = BN / 2;
  __shared__ __align__(16) bf16 As[2][128 * 64];
  __shared__ __align__(16) bf16 Bs[2][BN * 64];
  const int tid = threadIdx.x;
  const int w = tid >> 6, l = tid & 63;
  const int wr = w >> 1, wc = w & 1;
  const int nwg = gridDim.x;
  int bid = blockIdx.x;
  bid = (bid & 7) * (nwg >> 3) + (bid >> 3);
  const int nxb = N / BN;
  const int m0 = (bid / nxb) * 128, n0 = (bid % nxb) * BN;
  const int l15 = l & 15, l4 = l >> 4;
  const int srow = w * 8 + (l >> 3);
  const int sslot = (l & 7) ^ ((l >> 3) & 7);
  const int rsw = l15 & 7;
  f32x4 acc[4][NJ] = {};

  auto stage = [&](int k0, int b) {
    #pragma unroll
    for (int p = 0; p < 4; ++p) {
      const int row = p * 32 + srow;
      gload_lds16(A + (size_t)(m0 + row) * K + k0 + sslot * 8, &As[b][(p * 32 + w * 8) * 64] + l * 8);
    }
    #pragma unroll
    for (int p = 0; p < BN / 32; ++p) {
      const int row = p * 32 + srow;
      gload_lds16(Bt + (size_t)(n0 + row) * K + k0 + sslot * 8, &Bs[b][(p * 32 + w * 8) * 64] + l * 8);
    }
  };

  const int nt = K >> 6;
  stage(0, 0);
  __syncthreads();
  int bufi = 0;
  for (int t = 0; t < nt; ++t) {
    if (t + 1 < nt) stage((t + 1) << 6, bufi ^ 1);
    s16x8 af[4][2], bfr[NJ][2];
    #pragma unroll
    for (int i = 0; i < 4; ++i)
      #pragma unroll
      for (int h = 0; h < 2; ++h)
        af[i][h] = *(const s16x8*)(&As[bufi][(wr * 64 + i * 16 + l15) * 64] + (((h * 4 + l4) ^ rsw) * 8));
    #pragma unroll
    for (int j = 0; j < NJ; ++j)
      #pragma unroll
      for (int h = 0; h < 2; ++h)
        bfr[j][h] = *(const s16x8*)(&Bs[bufi][(wc * WN + j * 16 + l15) * 64] + (((h * 4 + l4) ^ rsw) * 8));
    #pragma unroll
    for (int i = 0; i < 4; ++i)
      #pragma unroll
      for (int j = 0; j < NJ; ++j) {
        acc[i][j] = __builtin_amdgcn_mfma_f32_16x16x32_bf16(af[i][0], bfr[j][0], acc[i][j], 0, 0, 0);
        acc[i][j] = __builtin_amdgcn_mfma_f32_16x16x32_bf16(af[i][1], bfr[j][1], acc[i][j], 0, 0, 0);
      }
    __syncthreads();
    bufi ^= 1;
  }

  if (EPI == 1) {
    #pragma unroll
    for (int i = 0; i < 4; ++i)
      #pragma unroll
      for (int j = 0; j < NJ; ++j) {
        const int ng = n0 + wc * WN + j * 16 + l15;
        const float bv = bias[ng];
        #pragma unroll
        for (int jj = 0; jj < 4; ++jj) {
          const int mg = m0 + wr * 64 + i * 16 + l4 * 4 + jj;
          outF[(size_t)mg * N + ng] = acc[i][j][jj] + bv;
        }
      }
  } else {
    const float SCL2 = 0.125f * 1.44269504089f;
    #pragma unroll
    for (int i = 0; i < 4; ++i)
      #pragma unroll
      for (int j = 0; j < NJ; ++j) {
        const int ng = n0 + wc * WN + j * 16 + l15;
        const int part = ng >> 10;
        const int d = ng & 63;
        const int h = (ng >> 6) & 15;
        const float bv = bias[ng];
        if (part == 2) {
          const int mg0 = m0 + wr * 64 + i * 16 + l4 * 4;
          const int t0 = mg0 & (T_ - 1);
          const int b = mg0 >> 11;
          u16x4 ov;
          #pragma unroll
          for (int jj = 0; jj < 4; ++jj) ov[jj] = f2bf_bits(acc[i][j][jj] + bv);
          *(u16x4*)(vb + ((size_t)(b * H_ + h) * DH_ + d) * T_ + t0) = ov;
        } else {
          #pragma unroll
          for (int jj = 0; jj < 4; ++jj) {
            const int mg = m0 + wr * 64 + i * 16 + l4 * 4 + jj;
            const int t = mg & (T_ - 1);
            const int b = mg >> 11;
            float v = acc[i][j][jj] + bv;
            float pp = __shfl_xor(v, 1);
            float2 csv = cs[t * 32 + (d >> 1)];
            float o = (d & 1) ? (v * csv.x + pp * csv.y) : (v * csv.x - pp * csv.y);
            if (part == 0) o *= SCL2;
            bf16* dst = (part == 0) ? qb : kb;
            dst[(size_t)((b * H_ + h) * T_ + t) * DH_ + d] = __float2bfloat16(o);
          }
        }
      }
  }
}

// ---------------- flash attention v8: r8 single-barrier schedule + r18 softmax + XCD-grouped KV ----------------
// K and V both double-buffered (64 KB, still 2 blocks/CU). stage(kt+1) issued at iter top;
// ONE barrier per tile at iter end -> prefetch overlaps the whole iteration (the 2-barrier
// form force-drained K(kt+1) at mid-iteration). Block mapping groups each XCD onto 4 bh
// (KV footprint 2 MB <= 4 MB L2) -> FETCH should drop ~2x.
__global__ __launch_bounds__(256, 2)
void attn_fwd(const bf16* __restrict__ qb, const bf16* __restrict__ kb,
              const bf16* __restrict__ vtb, bf16* __restrict__ y) {
  __shared__ __align__(16) bf16 Ks[2][KVB * 64];   // 32 KB
  __shared__ __align__(16) bf16 Vs[2][64 * KVB];   // 32 KB

  const int tid = threadIdx.x;
  const int w = tid >> 6, l = tid & 63;
  const int l15 = l & 15, l4 = l >> 4;
  // XCD-grouped mapping: xcd = bid&7 serves bh in [4*xcd, 4*xcd+4); heavy pi first
  const int xcd = blockIdx.x & 7;
  const int slot = blockIdx.x >> 3;                // 0..63
  const int bh = xcd * 4 + (slot & 3);
  const int pi = slot >> 2;                        // 0..15
  const int nkt = (33 - pi) >> 1;
  const int wqA = pi * 64 + w * 16;
  const int wqB = (31 - pi) * 64 + w * 16;

  const bf16* qp = qb + (size_t)bh * T_ * DH_;
  const bf16* kp = kb + (size_t)bh * T_ * DH_;
  const bf16* vtp = vtb + (size_t)bh * DH_ * T_;

  const s16x8 qA0 = *(const s16x8*)(qp + (size_t)(wqA + l15) * DH_ + l4 * 8);
  const s16x8 qA1 = *(const s16x8*)(qp + (size_t)(wqA + l15) * DH_ + l4 * 8 + 32);
  const s16x8 qB0 = *(const s16x8*)(qp + (size_t)(wqB + l15) * DH_ + l4 * 8);
  const s16x8 qB1 = *(const s16x8*)(qp + (size_t)(wqB + l15) * DH_ + l4 * 8 + 32);

  const int krow_ = tid >> 3, kslot_ = tid & 7;
  const int vrow_ = tid >> 4, vslot_ = tid & 15;

  auto stage = [&](int kt, int b) {
    const bf16* ksrc = kp + (size_t)kt * KVB * DH_;
    #pragma unroll
    for (int p = 0; p < 4; ++p) {
      const int r = p * 32 + krow_;
      gload_lds16(ksrc + (size_t)r * DH_ + ((kslot_ ^ (r & 7)) * 8),
                  &Ks[b][r * 64 + kslot_ * 8]);
    }
    #pragma unroll
    for (int p = 0; p < 4; ++p) {
      const int r = p * 16 + vrow_;
      gload_lds16(vtp + (size_t)r * T_ + kt * KVB + ((vslot_ ^ (r & 15)) * 8),
                  &Vs[b][r * KVB + vslot_ * 8]);
    }
  };

  f32x4 OA[4] = {}, OB[4] = {};
  float lsA = 0.0f, lsB = 0.0f;

  stage(0, 0);
  __syncthreads();

  int buf = 0;
  for (int kt = 0; kt < nkt; ++kt) {
    if (kt + 1 < nkt) stage(kt + 1, buf ^ 1);   // in flight across the WHOLE iteration
    const int k0 = kt * KVB;
    const bool actA = (k0 <= wqA + 15);

    f32x4 sA[8], sB[8];
    const int rsw = l15 & 7;
    __builtin_amdgcn_s_setprio(1);
    #pragma unroll
    for (int ks = 0; ks < 8; ++ks) {
      const bf16* krow = &Ks[buf][(ks * 16 + l15) * 64];
      const s16x8 kf0 = *(const s16x8*)(krow + ((l4 ^ rsw) * 8));
      const s16x8 kf1 = *(const s16x8*)(krow + (((4 + l4) ^ rsw) * 8));
      f32x4 t = {};
      t = __builtin_amdgcn_mfma_f32_16x16x32_bf16(kf0, qB0, t, 0, 0, 0);
      t = __builtin_amdgcn_mfma_f32_16x16x32_bf16(kf1, qB1, t, 0, 0, 0);
      sB[ks] = t;
      if (actA) {
        f32x4 u = {};
        u = __builtin_amdgcn_mfma_f32_16x16x32_bf16(kf0, qA0, u, 0, 0, 0);
        u = __builtin_amdgcn_mfma_f32_16x16x32_bf16(kf1, qA1, u, 0, 0, 0);
        sA[ks] = u;
      }
    }
    __builtin_amdgcn_s_setprio(0);

    auto softmax = [&](f32x4 (&s)[8], float& lsum, int wq) {
      if (k0 + KVB - 1 > wq) {
        const int q = wq + l15;
        #pragma unroll
        for (int ks = 0; ks < 8; ++ks)
          #pragma unroll
          for (int j = 0; j < 4; ++j)
            if (k0 + ks * 16 + l4 * 4 + j > q) s[ks][j] = -1e30f;
      }
      float ts = 0.0f;
      #pragma unroll
      for (int ks = 0; ks < 8; ++ks) {
        f32x4 pv;
        #pragma unroll
        for (int j = 0; j < 4; ++j) pv[j] = exp2f(s[ks][j]);   // scale pre-folded into q
        s[ks] = pv;
        ts += (pv[0] + pv[1]) + (pv[2] + pv[3]);
      }
      ts += __shfl_xor(ts, 16);
      ts += __shfl_xor(ts, 32);
      lsum += ts;
    };
    softmax(sB, lsB, wqB);
    if (actA) softmax(sA, lsA, wqA);

    __builtin_amdgcn_s_setprio(1);
    #pragma unroll
    for (int ks = 0; ks < 8; ++ks) {
      s16x4 pbB = {}, pbA = {};
      {
        u32x2 t2;
        t2.x = pk_trunc(sB[ks][0], sB[ks][1]);
        t2.y = pk_trunc(sB[ks][2], sB[ks][3]);
        pbB = __builtin_bit_cast(s16x4, t2);
      }
      if (actA) {
        u32x2 t2;
        t2.x = pk_trunc(sA[ks][0], sA[ks][1]);
        t2.y = pk_trunc(sA[ks][2], sA[ks][3]);
        pbA = __builtin_bit_cast(s16x4, t2);
      }
      const int slotb = ks * 2 + (l4 >> 1);
      const int inoff = (l4 & 1) * 8;
      #pragma unroll
      for (int dt = 0; dt < 4; ++dt) {
        const int d = dt * 16 + l15;
        const char* vrow = (const char*)&Vs[buf][d * KVB];
        u16x4 vf = *(const u16x4*)(vrow + ((slotb ^ (d & 15)) * 16 + inoff));
        OB[dt] = __builtin_amdgcn_mfma_f32_16x16x16bf16_1k(*(const s16x4*)&vf, pbB, OB[dt], 0, 0, 0);
        if (actA)
          OA[dt] = __builtin_amdgcn_mfma_f32_16x16x16bf16_1k(*(const s16x4*)&vf, pbA, OA[dt], 0, 0, 0);
      }
    }
    __builtin_amdgcn_s_setprio(0);

    __syncthreads();   // single barrier: stage(kt+1) landed; all reads of buf done
    buf ^= 1;
  }

  const int b = bh >> 4, h = bh & 15;
  auto writeO = [&](f32x4 (&O)[4], float lsum, int wq) {
    const float inv = 1.0f / lsum;
    bf16* yr = y + ((size_t)(b * T_ + wq + l15)) * D_ + h * DH_;
    #pragma unroll
    for (int dt = 0; dt < 4; ++dt) {
      u32x2 ov;
      ov.x = pk_trunc(O[dt][0] * inv, O[dt][1] * inv);
      ov.y = pk_trunc(O[dt][2] * inv, O[dt][3] * inv);
      *(u32x2*)(yr + dt * 16 + l4 * 4) = ov;
    }
  };
  writeO(OA, lsA, wqA);
  writeO(OB, lsB, wqB);
}

// ---------------- launcher ----------------

extern "C" void kernel_launch(void* const* d_in, const int* in_sizes, int n_in,
                              void* d_out, int out_size, void* d_ws, size_t ws_size,
                              hipStream_t stream) {
  (void)in_sizes; (void)n_in; (void)out_size; (void)ws_size;
  const float* x     = (const float*)d_in[0];
  const float* Wqkv  = (const float*)d_in[1];
  const float* bqkv  = (const float*)d_in[2];
  const float* Wproj = (const float*)d_in[3];
  const float* bproj = (const float*)d_in[4];
  float* outF = (float*)d_out;

  const size_t NTOK = (size_t)B_ * T_;
  const size_t NELM = NTOK * D_;

  char* p = (char*)d_ws;
  bf16* xb     = (bf16*)p; p += NELM * 2;
  bf16* wqkvT  = (bf16*)p; p += (size_t)3 * D_ * D_ * 2;
  bf16* wprojT = (bf16*)p; p += (size_t)D_ * D_ * 2;
  bf16* qbuf   = (bf16*)p; p += NELM * 2;                 // [B*H][T][DH]  (q pre-scaled)
  bf16* kbuf   = (bf16*)p; p += NELM * 2;                 // [B*H][T][DH]
  bf16* vtbuf  = (bf16*)p; p += NELM * 2;                 // [B*H][DH][T]
  bf16* ybuf   = (bf16*)p; p += NELM * 2;                 // [B][T][D]
  float2* cs   = (float2*)p; p += (size_t)T_ * 32 * sizeof(float2);

  k_prep<<<dim3(NB_CONV + NB_TQ + NB_TP + NB_ROPE), dim3(256), 0, stream>>>(
      x, xb, Wqkv, wqkvT, Wproj, wprojT, cs);

  gemm_bt<0, 192><<<dim3(512), dim3(256), 0, stream>>>(
      xb, wqkvT, bqkv, nullptr, qbuf, kbuf, vtbuf, cs, (int)NTOK, 3 * D_, D_);

  attn_fwd<<<dim3(512), dim3(256), 0, stream>>>(qbuf, kbuf, vtbuf, ybuf);

  gemm_bt<1, 128><<<dim3(8 * 32), dim3(256), 0, stream>>>(
      ybuf, wprojT, bproj, outF, nullptr, nullptr, nullptr, cs, (int)NTOK, D_, D_);
}

// Round 22
// 113.943 us; speedup vs baseline: 1.2353x; 1.0379x over previous
//
#include <hip/hip_runtime.h>
#include <hip/hip_bf16.h>

#define B_ 2
#define T_ 2048
#define H_ 16
#define DH_ 64
#define D_ 1024
#define KVB 128

typedef __hip_bfloat16 bf16;
typedef __attribute__((ext_vector_type(4))) float f32x4;
typedef __attribute__((ext_vector_type(8))) short s16x8;
typedef __attribute__((ext_vector_type(4))) short s16x4;
typedef __attribute__((ext_vector_type(4))) unsigned short u16x4;
typedef __attribute__((ext_vector_type(2))) unsigned int u32x2;

__device__ __forceinline__ unsigned short f2bf_bits(float f) {
  bf16 h = __float2bfloat16(f);
  return *reinterpret_cast<unsigned short*>(&h);
}

// pack two f32 -> two truncated bf16 in one v_perm_b32 (lo -> low16, hi -> high16)
__device__ __forceinline__ unsigned pk_trunc(float lo, float hi) {
  return __builtin_amdgcn_perm(__float_as_uint(hi), __float_as_uint(lo), 0x07060302u);
}

__device__ __forceinline__ void gload_lds16(const bf16* g, bf16* l) {
  __builtin_amdgcn_global_load_lds(
      (const __attribute__((address_space(1))) void*)g,
      (__attribute__((address_space(3))) void*)l, 16, 0, 0);
}

// ---------------- fused prep kernel ----------------
#define NB_CONV 4096
#define NB_TQ   3072
#define NB_TP   1024
#define NB_ROPE 256

__global__ __launch_bounds__(256)
void k_prep(const float* __restrict__ x, bf16* __restrict__ xb,
            const float* __restrict__ Wqkv, bf16* __restrict__ wqkvT,
            const float* __restrict__ Wproj, bf16* __restrict__ wprojT,
            float2* __restrict__ cs) {
  __shared__ float t[32][33];
  const int tid = threadIdx.x;
  int bid = blockIdx.x;
  if (bid < NB_CONV) {
    const int i = bid * 256 + tid;
    float4 v = reinterpret_cast<const float4*>(x)[i];
    u16x4 o;
    o[0] = f2bf_bits(v.x); o[1] = f2bf_bits(v.y);
    o[2] = f2bf_bits(v.z); o[3] = f2bf_bits(v.w);
    reinterpret_cast<u16x4*>(xb)[i] = o;
    return;
  }
  bid -= NB_CONV;
  if (bid < NB_TQ + NB_TP) {
    const float* in;
    bf16* out;
    int R, C, bx, by;
    if (bid < NB_TQ) { in = Wqkv; out = wqkvT; R = 1024; C = 3072; bx = bid % 96; by = bid / 96; }
    else { int tt = bid - NB_TQ; in = Wproj; out = wprojT; R = 1024; C = 1024; bx = tt & 31; by = tt >> 5; }
    const int c0 = bx * 32, r0 = by * 32;
    const int tx = tid & 31, ty = tid >> 5;
    #pragma unroll
    for (int i = 0; i < 32; i += 8)
      t[ty + i][tx] = in[(size_t)(r0 + ty + i) * C + (c0 + tx)];
    __syncthreads();
    #pragma unroll
    for (int i = 0; i < 32; i += 8)
      out[(size_t)(c0 + ty + i) * R + (r0 + tx)] = __float2bfloat16(t[tx][ty + i]);
    return;
  }
  bid -= NB_TQ + NB_TP;
  {
    const int i = bid * 256 + tid;
    const int tt = i >> 5, f = i & 31;
    const float NEG_L2_BASE_OVER_32 = -0.41524101186092f;  // -log2(10000)/32
    float inv = exp2f((float)f * NEG_L2_BASE_OVER_32);
    float a = (float)tt * inv;
    cs[i] = make_float2(__cosf(a), __sinf(a));
  }
}

// ---------------- GEMM: C = A[M][K] * (Bt[N][K])^T + bias ----------------
// BK=64 single-barrier dbuf + LDS slot swizzle (r15) + BN templated (r16) + BM templated (r22).
// EPI=0 (128x192): q pre-scaled by SCL2 (r17). EPI=1 (64x128): grid 512 = 2 blocks/CU.
template <int EPI, int BM, int BN>
__global__ __launch_bounds__(256, 2)
void gemm_bt(const bf16* __restrict__ A, const bf16* __restrict__ Bt,
             const float* __restrict__ bias, float* __restrict__ outF,
             bf16* __restrict__ qb, bf16* __restrict__ kb, bf16* __restrict__ vb,
             const float2* __restrict__ cs, int M, int N, int K) {
  constexpr int MI = BM / 32;           // per-wave m-subtiles (wave-row covers BM/2)
  constexpr int NJ = BN / 32;           // per-wave n-subtiles (wave-col covers BN/2)
  constexpr int WM = BM / 2;
  constexpr int WN = BN / 2;
  __shared__ __align__(16) bf16 As[2][BM * 64];
  __shared__ __align__(16) bf16 Bs[2][BN * 64];
  const int tid = threadIdx.x;
  const int w = tid >> 6, l = tid & 63;
  const int wr = w >> 1, wc = w & 1;
  const int nwg = gridDim.x;
  int bid = blockIdx.x;
  bid = (bid & 7) * (nwg >> 3) + (bid >> 3);
  const int nxb = N / BN;
  const int m0 = (bid / nxb) * BM, n0 = (bid % nxb) * BN;
  const int l15 = l & 15, l4 = l >> 4;
  const int srow = w * 8 + (l >> 3);
  const int sslot = (l & 7) ^ ((l >> 3) & 7);
  const int rsw = l15 & 7;
  f32x4 acc[MI][NJ] = {};

  auto stage = [&](int k0, int b) {
    #pragma unroll
    for (int p = 0; p < BM / 32; ++p) {
      const int row = p * 32 + srow;
      gload_lds16(A + (size_t)(m0 + row) * K + k0 + sslot * 8, &As[b][(p * 32 + w * 8) * 64] + l * 8);
    }
    #pragma unroll
    for (int p = 0; p < BN / 32; ++p) {
      const int row = p * 32 + srow;
      gload_lds16(Bt + (size_t)(n0 + row) * K + k0 + sslot * 8, &Bs[b][(p * 32 + w * 8) * 64] + l * 8);
    }
  };

  const int nt = K >> 6;
  stage(0, 0);
  __syncthreads();
  int bufi = 0;
  for (int t = 0; t < nt; ++t) {
    if (t + 1 < nt) stage((t + 1) << 6, bufi ^ 1);
    s16x8 af[MI][2], bfr[NJ][2];
    #pragma unroll
    for (int i = 0; i < MI; ++i)
      #pragma unroll
      for (int h = 0; h < 2; ++h)
        af[i][h] = *(const s16x8*)(&As[bufi][(wr * WM + i * 16 + l15) * 64] + (((h * 4 + l4) ^ rsw) * 8));
    #pragma unroll
    for (int j = 0; j < NJ; ++j)
      #pragma unroll
      for (int h = 0; h < 2; ++h)
        bfr[j][h] = *(const s16x8*)(&Bs[bufi][(wc * WN + j * 16 + l15) * 64] + (((h * 4 + l4) ^ rsw) * 8));
    #pragma unroll
    for (int i = 0; i < MI; ++i)
      #pragma unroll
      for (int j = 0; j < NJ; ++j) {
        acc[i][j] = __builtin_amdgcn_mfma_f32_16x16x32_bf16(af[i][0], bfr[j][0], acc[i][j], 0, 0, 0);
        acc[i][j] = __builtin_amdgcn_mfma_f32_16x16x32_bf16(af[i][1], bfr[j][1], acc[i][j], 0, 0, 0);
      }
    __syncthreads();
    bufi ^= 1;
  }

  if (EPI == 1) {
    #pragma unroll
    for (int i = 0; i < MI; ++i)
      #pragma unroll
      for (int j = 0; j < NJ; ++j) {
        const int ng = n0 + wc * WN + j * 16 + l15;
        const float bv = bias[ng];
        #pragma unroll
        for (int jj = 0; jj < 4; ++jj) {
          const int mg = m0 + wr * WM + i * 16 + l4 * 4 + jj;
          outF[(size_t)mg * N + ng] = acc[i][j][jj] + bv;
        }
      }
  } else {
    const float SCL2 = 0.125f * 1.44269504089f;
    #pragma unroll
    for (int i = 0; i < MI; ++i)
      #pragma unroll
      for (int j = 0; j < NJ; ++j) {
        const int ng = n0 + wc * WN + j * 16 + l15;
        const int part = ng >> 10;
        const int d = ng & 63;
        const int h = (ng >> 6) & 15;
        const float bv = bias[ng];
        if (part == 2) {
          const int mg0 = m0 + wr * WM + i * 16 + l4 * 4;
          const int t0 = mg0 & (T_ - 1);
          const int b = mg0 >> 11;
          u16x4 ov;
          #pragma unroll
          for (int jj = 0; jj < 4; ++jj) ov[jj] = f2bf_bits(acc[i][j][jj] + bv);
          *(u16x4*)(vb + ((size_t)(b * H_ + h) * DH_ + d) * T_ + t0) = ov;
        } else {
          #pragma unroll
          for (int jj = 0; jj < 4; ++jj) {
            const int mg = m0 + wr * WM + i * 16 + l4 * 4 + jj;
            const int t = mg & (T_ - 1);
            const int b = mg >> 11;
            float v = acc[i][j][jj] + bv;
            float pp = __shfl_xor(v, 1);
            float2 csv = cs[t * 32 + (d >> 1)];
            float o = (d & 1) ? (v * csv.x + pp * csv.y) : (v * csv.x - pp * csv.y);
            if (part == 0) o *= SCL2;
            bf16* dst = (part == 0) ? qb : kb;
            dst[(size_t)((b * H_ + h) * T_ + t) * DH_ + d] = __float2bfloat16(o);
          }
        }
      }
  }
}

// ---------------- flash attention v8b: r21 + deferred lsum reduce ----------------
// Per-lane partial lsum accumulated across all tiles; single cross-lane reduce
// (shfl_xor 16/32) in the epilogue. Saves 2 shfl per softmax call.
__global__ __launch_bounds__(256, 2)
void attn_fwd(const bf16* __restrict__ qb, const bf16* __restrict__ kb,
              const bf16* __restrict__ vtb, bf16* __restrict__ y) {
  __shared__ __align__(16) bf16 Ks[2][KVB * 64];   // 32 KB
  __shared__ __align__(16) bf16 Vs[2][64 * KVB];   // 32 KB

  const int tid = threadIdx.x;
  const int w = tid >> 6, l = tid & 63;
  const int l15 = l & 15, l4 = l >> 4;
  // XCD-grouped mapping (r21 WIN: FETCH 63.6->12.4 MB)
  const int xcd = blockIdx.x & 7;
  const int slot = blockIdx.x >> 3;                // 0..63
  const int bh = xcd * 4 + (slot & 3);
  const int pi = slot >> 2;                        // 0..15
  const int nkt = (33 - pi) >> 1;
  const int wqA = pi * 64 + w * 16;
  const int wqB = (31 - pi) * 64 + w * 16;

  const bf16* qp = qb + (size_t)bh * T_ * DH_;
  const bf16* kp = kb + (size_t)bh * T_ * DH_;
  const bf16* vtp = vtb + (size_t)bh * DH_ * T_;

  const s16x8 qA0 = *(const s16x8*)(qp + (size_t)(wqA + l15) * DH_ + l4 * 8);
  const s16x8 qA1 = *(const s16x8*)(qp + (size_t)(wqA + l15) * DH_ + l4 * 8 + 32);
  const s16x8 qB0 = *(const s16x8*)(qp + (size_t)(wqB + l15) * DH_ + l4 * 8);
  const s16x8 qB1 = *(const s16x8*)(qp + (size_t)(wqB + l15) * DH_ + l4 * 8 + 32);

  const int krow_ = tid >> 3, kslot_ = tid & 7;
  const int vrow_ = tid >> 4, vslot_ = tid & 15;

  auto stage = [&](int kt, int b) {
    const bf16* ksrc = kp + (size_t)kt * KVB * DH_;
    #pragma unroll
    for (int p = 0; p < 4; ++p) {
      const int r = p * 32 + krow_;
      gload_lds16(ksrc + (size_t)r * DH_ + ((kslot_ ^ (r & 7)) * 8),
                  &Ks[b][r * 64 + kslot_ * 8]);
    }
    #pragma unroll
    for (int p = 0; p < 4; ++p) {
      const int r = p * 16 + vrow_;
      gload_lds16(vtp + (size_t)r * T_ + kt * KVB + ((vslot_ ^ (r & 15)) * 8),
                  &Vs[b][r * KVB + vslot_ * 8]);
    }
  };

  f32x4 OA[4] = {}, OB[4] = {};
  float lsA = 0.0f, lsB = 0.0f;   // per-LANE partials; reduced once in epilogue

  stage(0, 0);
  __syncthreads();

  int buf = 0;
  for (int kt = 0; kt < nkt; ++kt) {
    if (kt + 1 < nkt) stage(kt + 1, buf ^ 1);   // in flight across the WHOLE iteration
    const int k0 = kt * KVB;
    const bool actA = (k0 <= wqA + 15);

    f32x4 sA[8], sB[8];
    const int rsw = l15 & 7;
    __builtin_amdgcn_s_setprio(1);
    #pragma unroll
    for (int ks = 0; ks < 8; ++ks) {
      const bf16* krow = &Ks[buf][(ks * 16 + l15) * 64];
      const s16x8 kf0 = *(const s16x8*)(krow + ((l4 ^ rsw) * 8));
      const s16x8 kf1 = *(const s16x8*)(krow + (((4 + l4) ^ rsw) * 8));
      f32x4 t = {};
      t = __builtin_amdgcn_mfma_f32_16x16x32_bf16(kf0, qB0, t, 0, 0, 0);
      t = __builtin_amdgcn_mfma_f32_16x16x32_bf16(kf1, qB1, t, 0, 0, 0);
      sB[ks] = t;
      if (actA) {
        f32x4 u = {};
        u = __builtin_amdgcn_mfma_f32_16x16x32_bf16(kf0, qA0, u, 0, 0, 0);
        u = __builtin_amdgcn_mfma_f32_16x16x32_bf16(kf1, qA1, u, 0, 0, 0);
        sA[ks] = u;
      }
    }
    __builtin_amdgcn_s_setprio(0);

    auto softmax = [&](f32x4 (&s)[8], float& lsum, int wq) {
      if (k0 + KVB - 1 > wq) {
        const int q = wq + l15;
        #pragma unroll
        for (int ks = 0; ks < 8; ++ks)
          #pragma unroll
          for (int j = 0; j < 4; ++j)
            if (k0 + ks * 16 + l4 * 4 + j > q) s[ks][j] = -1e30f;
      }
      float ts = 0.0f;
      #pragma unroll
      for (int ks = 0; ks < 8; ++ks) {
        f32x4 pv;
        #pragma unroll
        for (int j = 0; j < 4; ++j) pv[j] = exp2f(s[ks][j]);   // scale pre-folded into q
        s[ks] = pv;
        ts += (pv[0] + pv[1]) + (pv[2] + pv[3]);
      }
      lsum += ts;   // per-lane partial; cross-lane reduce deferred to epilogue
    };
    softmax(sB, lsB, wqB);
    if (actA) softmax(sA, lsA, wqA);

    __builtin_amdgcn_s_setprio(1);
    #pragma unroll
    for (int ks = 0; ks < 8; ++ks) {
      s16x4 pbB = {}, pbA = {};
      {
        u32x2 t2;
        t2.x = pk_trunc(sB[ks][0], sB[ks][1]);
        t2.y = pk_trunc(sB[ks][2], sB[ks][3]);
        pbB = __builtin_bit_cast(s16x4, t2);
      }
      if (actA) {
        u32x2 t2;
        t2.x = pk_trunc(sA[ks][0], sA[ks][1]);
        t2.y = pk_trunc(sA[ks][2], sA[ks][3]);
        pbA = __builtin_bit_cast(s16x4, t2);
      }
      const int slotb = ks * 2 + (l4 >> 1);
      const int inoff = (l4 & 1) * 8;
      #pragma unroll
      for (int dt = 0; dt < 4; ++dt) {
        const int d = dt * 16 + l15;
        const char* vrow = (const char*)&Vs[buf][d * KVB];
        u16x4 vf = *(const u16x4*)(vrow + ((slotb ^ (d & 15)) * 16 + inoff));
        OB[dt] = __builtin_amdgcn_mfma_f32_16x16x16bf16_1k(*(const s16x4*)&vf, pbB, OB[dt], 0, 0, 0);
        if (actA)
          OA[dt] = __builtin_amdgcn_mfma_f32_16x16x16bf16_1k(*(const s16x4*)&vf, pbA, OA[dt], 0, 0, 0);
      }
    }
    __builtin_amdgcn_s_setprio(0);

    __syncthreads();   // single barrier: stage(kt+1) landed; all reads of buf done
    buf ^= 1;
  }

  // one cross-lane reduce for the whole kernel (lanes {q, q+16, q+32, q+48})
  lsB += __shfl_xor(lsB, 16); lsB += __shfl_xor(lsB, 32);
  lsA += __shfl_xor(lsA, 16); lsA += __shfl_xor(lsA, 32);

  const int b = bh >> 4, h = bh & 15;
  auto writeO = [&](f32x4 (&O)[4], float lsum, int wq) {
    const float inv = 1.0f / lsum;
    bf16* yr = y + ((size_t)(b * T_ + wq + l15)) * D_ + h * DH_;
    #pragma unroll
    for (int dt = 0; dt < 4; ++dt) {
      u32x2 ov;
      ov.x = pk_trunc(O[dt][0] * inv, O[dt][1] * inv);
      ov.y = pk_trunc(O[dt][2] * inv, O[dt][3] * inv);
      *(u32x2*)(yr + dt * 16 + l4 * 4) = ov;
    }
  };
  writeO(OA, lsA, wqA);
  writeO(OB, lsB, wqB);
}

// ---------------- launcher ----------------

extern "C" void kernel_launch(void* const* d_in, const int* in_sizes, int n_in,
                              void* d_out, int out_size, void* d_ws, size_t ws_size,
                              hipStream_t stream) {
  (void)in_sizes; (void)n_in; (void)out_size; (void)ws_size;
  const float* x     = (const float*)d_in[0];
  const float* Wqkv  = (const float*)d_in[1];
  const float* bqkv  = (const float*)d_in[2];
  const float* Wproj = (const float*)d_in[3];
  const float* bproj = (const float*)d_in[4];
  float* outF = (float*)d_out;

  const size_t NTOK = (size_t)B_ * T_;
  const size_t NELM = NTOK * D_;

  char* p = (char*)d_ws;
  bf16* xb     = (bf16*)p; p += NELM * 2;
  bf16* wqkvT  = (bf16*)p; p += (size_t)3 * D_ * D_ * 2;
  bf16* wprojT = (bf16*)p; p += (size_t)D_ * D_ * 2;
  bf16* qbuf   = (bf16*)p; p += NELM * 2;                 // [B*H][T][DH]  (q pre-scaled)
  bf16* kbuf   = (bf16*)p; p += NELM * 2;                 // [B*H][T][DH]
  bf16* vtbuf  = (bf16*)p; p += NELM * 2;                 // [B*H][DH][T]
  bf16* ybuf   = (bf16*)p; p += NELM * 2;                 // [B][T][D]
  float2* cs   = (float2*)p; p += (size_t)T_ * 32 * sizeof(float2);

  k_prep<<<dim3(NB_CONV + NB_TQ + NB_TP + NB_ROPE), dim3(256), 0, stream>>>(
      x, xb, Wqkv, wqkvT, Wproj, wprojT, cs);

  gemm_bt<0, 128, 192><<<dim3(512), dim3(256), 0, stream>>>(
      xb, wqkvT, bqkv, nullptr, qbuf, kbuf, vtbuf, cs, (int)NTOK, 3 * D_, D_);

  attn_fwd<<<dim3(512), dim3(256), 0, stream>>>(qbuf, kbuf, vtbuf, ybuf);

  gemm_bt<1, 64, 128><<<dim3(512), dim3(256), 0, stream>>>(
      ybuf, wprojT, bproj, outF, nullptr, nullptr, nullptr, cs, (int)NTOK, D_, D_);
}

// Round 23
// 110.113 us; speedup vs baseline: 1.2783x; 1.0348x over previous
//
#include <hip/hip_runtime.h>
#include <hip/hip_bf16.h>

#define B_ 2
#define T_ 2048
#define H_ 16
#define DH_ 64
#define D_ 1024
#define KVB 128

typedef __hip_bfloat16 bf16;
typedef __attribute__((ext_vector_type(4))) float f32x4;
typedef __attribute__((ext_vector_type(8))) short s16x8;
typedef __attribute__((ext_vector_type(4))) short s16x4;
typedef __attribute__((ext_vector_type(4))) unsigned short u16x4;
typedef __attribute__((ext_vector_type(2))) unsigned int u32x2;

__device__ __forceinline__ unsigned short f2bf_bits(float f) {
  bf16 h = __float2bfloat16(f);
  return *reinterpret_cast<unsigned short*>(&h);
}

// pack two f32 -> two truncated bf16 in one v_perm_b32 (lo -> low16, hi -> high16)
__device__ __forceinline__ unsigned pk_trunc(float lo, float hi) {
  return __builtin_amdgcn_perm(__float_as_uint(hi), __float_as_uint(lo), 0x07060302u);
}

__device__ __forceinline__ void gload_lds16(const bf16* g, bf16* l) {
  __builtin_amdgcn_global_load_lds(
      (const __attribute__((address_space(1))) void*)g,
      (__attribute__((address_space(3))) void*)l, 16, 0, 0);
}

// ---------------- fused prep kernel ----------------
#define NB_CONV 4096
#define NB_TQ   3072
#define NB_TP   1024
#define NB_ROPE 256

__global__ __launch_bounds__(256)
void k_prep(const float* __restrict__ x, bf16* __restrict__ xb,
            const float* __restrict__ Wqkv, bf16* __restrict__ wqkvT,
            const float* __restrict__ Wproj, bf16* __restrict__ wprojT,
            float2* __restrict__ cs) {
  __shared__ float t[32][33];
  const int tid = threadIdx.x;
  int bid = blockIdx.x;
  if (bid < NB_CONV) {
    const int i = bid * 256 + tid;
    float4 v = reinterpret_cast<const float4*>(x)[i];
    u16x4 o;
    o[0] = f2bf_bits(v.x); o[1] = f2bf_bits(v.y);
    o[2] = f2bf_bits(v.z); o[3] = f2bf_bits(v.w);
    reinterpret_cast<u16x4*>(xb)[i] = o;
    return;
  }
  bid -= NB_CONV;
  if (bid < NB_TQ + NB_TP) {
    const float* in;
    bf16* out;
    int R, C, bx, by;
    if (bid < NB_TQ) { in = Wqkv; out = wqkvT; R = 1024; C = 3072; bx = bid % 96; by = bid / 96; }
    else { int tt = bid - NB_TQ; in = Wproj; out = wprojT; R = 1024; C = 1024; bx = tt & 31; by = tt >> 5; }
    const int c0 = bx * 32, r0 = by * 32;
    // vectorized 32x32 transpose: 1 float4 load + 1 8B bf16 store per thread
    const int row = tid >> 3, col4 = (tid & 7) * 4;
    float4 v = *reinterpret_cast<const float4*>(&in[(size_t)(r0 + row) * C + (c0 + col4)]);
    t[row][col4 + 0] = v.x; t[row][col4 + 1] = v.y;
    t[row][col4 + 2] = v.z; t[row][col4 + 3] = v.w;
    __syncthreads();
    u16x4 o;
    o[0] = f2bf_bits(t[col4 + 0][row]);
    o[1] = f2bf_bits(t[col4 + 1][row]);
    o[2] = f2bf_bits(t[col4 + 2][row]);
    o[3] = f2bf_bits(t[col4 + 3][row]);
    // out[c0+row][r0+col4 .. +3]  ... wait: we need out[c][r] = in[r][c].
    // thread writes out row (c0+row), cols r0+col4..+3 -> value in[r0+col4+i][c0+row] = t[col4+i][row]
    *reinterpret_cast<u16x4*>(&out[(size_t)(c0 + row) * R + (r0 + col4)]) = o;
    return;
  }
  bid -= NB_TQ + NB_TP;
  {
    const int i = bid * 256 + tid;
    const int tt = i >> 5, f = i & 31;
    const float NEG_L2_BASE_OVER_32 = -0.41524101186092f;  // -log2(10000)/32
    float inv = exp2f((float)f * NEG_L2_BASE_OVER_32);
    float a = (float)tt * inv;
    cs[i] = make_float2(__cosf(a), __sinf(a));
  }
}

// ---------------- GEMM: C = A[M][K] * (Bt[N][K])^T + bias ----------------
// BK=64 single-barrier dbuf + LDS slot swizzle (r15) + BM/BN templated (r16/r22).
// r23: fragment ds_reads issued BEFORE the stage burst (globals slide into MFMA shadow).
template <int EPI, int BM, int BN>
__global__ __launch_bounds__(256, 2)
void gemm_bt(const bf16* __restrict__ A, const bf16* __restrict__ Bt,
             const float* __restrict__ bias, float* __restrict__ outF,
             bf16* __restrict__ qb, bf16* __restrict__ kb, bf16* __restrict__ vb,
             const float2* __restrict__ cs, int M, int N, int K) {
  constexpr int MI = BM / 32;
  constexpr int NJ = BN / 32;
  constexpr int WM = BM / 2;
  constexpr int WN = BN / 2;
  __shared__ __align__(16) bf16 As[2][BM * 64];
  __shared__ __align__(16) bf16 Bs[2][BN * 64];
  const int tid = threadIdx.x;
  const int w = tid >> 6, l = tid & 63;
  const int wr = w >> 1, wc = w & 1;
  const int nwg = gridDim.x;
  int bid = blockIdx.x;
  bid = (bid & 7) * (nwg >> 3) + (bid >> 3);
  const int nxb = N / BN;
  const int m0 = (bid / nxb) * BM, n0 = (bid % nxb) * BN;
  const int l15 = l & 15, l4 = l >> 4;
  const int srow = w * 8 + (l >> 3);
  const int sslot = (l & 7) ^ ((l >> 3) & 7);
  const int rsw = l15 & 7;
  f32x4 acc[MI][NJ] = {};

  auto stage = [&](int k0, int b) {
    #pragma unroll
    for (int p = 0; p < BM / 32; ++p) {
      const int row = p * 32 + srow;
      gload_lds16(A + (size_t)(m0 + row) * K + k0 + sslot * 8, &As[b][(p * 32 + w * 8) * 64] + l * 8);
    }
    #pragma unroll
    for (int p = 0; p < BN / 32; ++p) {
      const int row = p * 32 + srow;
      gload_lds16(Bt + (size_t)(n0 + row) * K + k0 + sslot * 8, &Bs[b][(p * 32 + w * 8) * 64] + l * 8);
    }
  };

  const int nt = K >> 6;
  stage(0, 0);
  __syncthreads();
  int bufi = 0;
  for (int t = 0; t < nt; ++t) {
    // fragment ds_reads FIRST: MFMA can start on partial lgkmcnt while globals issue
    s16x8 af[MI][2], bfr[NJ][2];
    #pragma unroll
    for (int i = 0; i < MI; ++i)
      #pragma unroll
      for (int h = 0; h < 2; ++h)
        af[i][h] = *(const s16x8*)(&As[bufi][(wr * WM + i * 16 + l15) * 64] + (((h * 4 + l4) ^ rsw) * 8));
    #pragma unroll
    for (int j = 0; j < NJ; ++j)
      #pragma unroll
      for (int h = 0; h < 2; ++h)
        bfr[j][h] = *(const s16x8*)(&Bs[bufi][(wc * WN + j * 16 + l15) * 64] + (((h * 4 + l4) ^ rsw) * 8));
    if (t + 1 < nt) stage((t + 1) << 6, bufi ^ 1);
    #pragma unroll
    for (int i = 0; i < MI; ++i)
      #pragma unroll
      for (int j = 0; j < NJ; ++j) {
        acc[i][j] = __builtin_amdgcn_mfma_f32_16x16x32_bf16(af[i][0], bfr[j][0], acc[i][j], 0, 0, 0);
        acc[i][j] = __builtin_amdgcn_mfma_f32_16x16x32_bf16(af[i][1], bfr[j][1], acc[i][j], 0, 0, 0);
      }
    __syncthreads();
    bufi ^= 1;
  }

  if (EPI == 1) {
    #pragma unroll
    for (int i = 0; i < MI; ++i)
      #pragma unroll
      for (int j = 0; j < NJ; ++j) {
        const int ng = n0 + wc * WN + j * 16 + l15;
        const float bv = bias[ng];
        #pragma unroll
        for (int jj = 0; jj < 4; ++jj) {
          const int mg = m0 + wr * WM + i * 16 + l4 * 4 + jj;
          outF[(size_t)mg * N + ng] = acc[i][j][jj] + bv;
        }
      }
  } else {
    const float SCL2 = 0.125f * 1.44269504089f;
    #pragma unroll
    for (int i = 0; i < MI; ++i)
      #pragma unroll
      for (int j = 0; j < NJ; ++j) {
        const int ng = n0 + wc * WN + j * 16 + l15;
        const int part = ng >> 10;
        const int d = ng & 63;
        const int h = (ng >> 6) & 15;
        const float bv = bias[ng];
        if (part == 2) {
          const int mg0 = m0 + wr * WM + i * 16 + l4 * 4;
          const int t0 = mg0 & (T_ - 1);
          const int b = mg0 >> 11;
          u16x4 ov;
          #pragma unroll
          for (int jj = 0; jj < 4; ++jj) ov[jj] = f2bf_bits(acc[i][j][jj] + bv);
          *(u16x4*)(vb + ((size_t)(b * H_ + h) * DH_ + d) * T_ + t0) = ov;
        } else {
          #pragma unroll
          for (int jj = 0; jj < 4; ++jj) {
            const int mg = m0 + wr * WM + i * 16 + l4 * 4 + jj;
            const int t = mg & (T_ - 1);
            const int b = mg >> 11;
            float v = acc[i][j][jj] + bv;
            float pp = __shfl_xor(v, 1);
            float2 csv = cs[t * 32 + (d >> 1)];
            float o = (d & 1) ? (v * csv.x + pp * csv.y) : (v * csv.x - pp * csv.y);
            if (part == 0) o *= SCL2;
            bf16* dst = (part == 0) ? qb : kb;
            dst[(size_t)((b * H_ + h) * T_ + t) * DH_ + d] = __float2bfloat16(o);
          }
        }
      }
  }
}

// ---------------- flash attention v8c: r22 + stage issued after QK^T ----------------
__global__ __launch_bounds__(256, 2)
void attn_fwd(const bf16* __restrict__ qb, const bf16* __restrict__ kb,
              const bf16* __restrict__ vtb, bf16* __restrict__ y) {
  __shared__ __align__(16) bf16 Ks[2][KVB * 64];   // 32 KB
  __shared__ __align__(16) bf16 Vs[2][64 * KVB];   // 32 KB

  const int tid = threadIdx.x;
  const int w = tid >> 6, l = tid & 63;
  const int l15 = l & 15, l4 = l >> 4;
  // XCD-grouped mapping (r21 WIN: FETCH 63.6->12.4 MB)
  const int xcd = blockIdx.x & 7;
  const int slot = blockIdx.x >> 3;
  const int bh = xcd * 4 + (slot & 3);
  const int pi = slot >> 2;
  const int nkt = (33 - pi) >> 1;
  const int wqA = pi * 64 + w * 16;
  const int wqB = (31 - pi) * 64 + w * 16;

  const bf16* qp = qb + (size_t)bh * T_ * DH_;
  const bf16* kp = kb + (size_t)bh * T_ * DH_;
  const bf16* vtp = vtb + (size_t)bh * DH_ * T_;

  const s16x8 qA0 = *(const s16x8*)(qp + (size_t)(wqA + l15) * DH_ + l4 * 8);
  const s16x8 qA1 = *(const s16x8*)(qp + (size_t)(wqA + l15) * DH_ + l4 * 8 + 32);
  const s16x8 qB0 = *(const s16x8*)(qp + (size_t)(wqB + l15) * DH_ + l4 * 8);
  const s16x8 qB1 = *(const s16x8*)(qp + (size_t)(wqB + l15) * DH_ + l4 * 8 + 32);

  const int krow_ = tid >> 3, kslot_ = tid & 7;
  const int vrow_ = tid >> 4, vslot_ = tid & 15;

  auto stage = [&](int kt, int b) {
    const bf16* ksrc = kp + (size_t)kt * KVB * DH_;
    #pragma unroll
    for (int p = 0; p < 4; ++p) {
      const int r = p * 32 + krow_;
      gload_lds16(ksrc + (size_t)r * DH_ + ((kslot_ ^ (r & 7)) * 8),
                  &Ks[b][r * 64 + kslot_ * 8]);
    }
    #pragma unroll
    for (int p = 0; p < 4; ++p) {
      const int r = p * 16 + vrow_;
      gload_lds16(vtp + (size_t)r * T_ + kt * KVB + ((vslot_ ^ (r & 15)) * 8),
                  &Vs[b][r * KVB + vslot_ * 8]);
    }
  };

  f32x4 OA[4] = {}, OB[4] = {};
  float lsA = 0.0f, lsB = 0.0f;   // per-lane partials; reduced once in epilogue

  stage(0, 0);
  __syncthreads();

  int buf = 0;
  for (int kt = 0; kt < nkt; ++kt) {
    const int k0 = kt * KVB;
    const bool actA = (k0 <= wqA + 15);

    // QK^T first (ds_read + MFMA), stage burst issued after, into the softmax shadow
    f32x4 sA[8], sB[8];
    const int rsw = l15 & 7;
    __builtin_amdgcn_s_setprio(1);
    #pragma unroll
    for (int ks = 0; ks < 8; ++ks) {
      const bf16* krow = &Ks[buf][(ks * 16 + l15) * 64];
      const s16x8 kf0 = *(const s16x8*)(krow + ((l4 ^ rsw) * 8));
      const s16x8 kf1 = *(const s16x8*)(krow + (((4 + l4) ^ rsw) * 8));
      f32x4 t = {};
      t = __builtin_amdgcn_mfma_f32_16x16x32_bf16(kf0, qB0, t, 0, 0, 0);
      t = __builtin_amdgcn_mfma_f32_16x16x32_bf16(kf1, qB1, t, 0, 0, 0);
      sB[ks] = t;
      if (actA) {
        f32x4 u = {};
        u = __builtin_amdgcn_mfma_f32_16x16x32_bf16(kf0, qA0, u, 0, 0, 0);
        u = __builtin_amdgcn_mfma_f32_16x16x32_bf16(kf1, qA1, u, 0, 0, 0);
        sA[ks] = u;
      }
    }
    __builtin_amdgcn_s_setprio(0);

    if (kt + 1 < nkt) stage(kt + 1, buf ^ 1);   // issues under softmax + PV

    auto softmax = [&](f32x4 (&s)[8], float& lsum, int wq) {
      if (k0 + KVB - 1 > wq) {
        const int q = wq + l15;
        #pragma unroll
        for (int ks = 0; ks < 8; ++ks)
          #pragma unroll
          for (int j = 0; j < 4; ++j)
            if (k0 + ks * 16 + l4 * 4 + j > q) s[ks][j] = -1e30f;
      }
      float ts = 0.0f;
      #pragma unroll
      for (int ks = 0; ks < 8; ++ks) {
        f32x4 pv;
        #pragma unroll
        for (int j = 0; j < 4; ++j) pv[j] = exp2f(s[ks][j]);   // scale pre-folded into q
        s[ks] = pv;
        ts += (pv[0] + pv[1]) + (pv[2] + pv[3]);
      }
      lsum += ts;   // per-lane partial; cross-lane reduce deferred to epilogue
    };
    softmax(sB, lsB, wqB);
    if (actA) softmax(sA, lsA, wqA);

    __builtin_amdgcn_s_setprio(1);
    #pragma unroll
    for (int ks = 0; ks < 8; ++ks) {
      s16x4 pbB = {}, pbA = {};
      {
        u32x2 t2;
        t2.x = pk_trunc(sB[ks][0], sB[ks][1]);
        t2.y = pk_trunc(sB[ks][2], sB[ks][3]);
        pbB = __builtin_bit_cast(s16x4, t2);
      }
      if (actA) {
        u32x2 t2;
        t2.x = pk_trunc(sA[ks][0], sA[ks][1]);
        t2.y = pk_trunc(sA[ks][2], sA[ks][3]);
        pbA = __builtin_bit_cast(s16x4, t2);
      }
      const int slotb = ks * 2 + (l4 >> 1);
      const int inoff = (l4 & 1) * 8;
      #pragma unroll
      for (int dt = 0; dt < 4; ++dt) {
        const int d = dt * 16 + l15;
        const char* vrow = (const char*)&Vs[buf][d * KVB];
        u16x4 vf = *(const u16x4*)(vrow + ((slotb ^ (d & 15)) * 16 + inoff));
        OB[dt] = __builtin_amdgcn_mfma_f32_16x16x16bf16_1k(*(const s16x4*)&vf, pbB, OB[dt], 0, 0, 0);
        if (actA)
          OA[dt] = __builtin_amdgcn_mfma_f32_16x16x16bf16_1k(*(const s16x4*)&vf, pbA, OA[dt], 0, 0, 0);
      }
    }
    __builtin_amdgcn_s_setprio(0);

    __syncthreads();   // single barrier: stage(kt+1) landed; all reads of buf done
    buf ^= 1;
  }

  // one cross-lane reduce for the whole kernel (lanes {q, q+16, q+32, q+48})
  lsB += __shfl_xor(lsB, 16); lsB += __shfl_xor(lsB, 32);
  lsA += __shfl_xor(lsA, 16); lsA += __shfl_xor(lsA, 32);

  const int b = bh >> 4, h = bh & 15;
  auto writeO = [&](f32x4 (&O)[4], float lsum, int wq) {
    const float inv = 1.0f / lsum;
    bf16* yr = y + ((size_t)(b * T_ + wq + l15)) * D_ + h * DH_;
    #pragma unroll
    for (int dt = 0; dt < 4; ++dt) {
      u32x2 ov;
      ov.x = pk_trunc(O[dt][0] * inv, O[dt][1] * inv);
      ov.y = pk_trunc(O[dt][2] * inv, O[dt][3] * inv);
      *(u32x2*)(yr + dt * 16 + l4 * 4) = ov;
    }
  };
  writeO(OA, lsA, wqA);
  writeO(OB, lsB, wqB);
}

// ---------------- launcher ----------------

extern "C" void kernel_launch(void* const* d_in, const int* in_sizes, int n_in,
                              void* d_out, int out_size, void* d_ws, size_t ws_size,
                              hipStream_t stream) {
  (void)in_sizes; (void)n_in; (void)out_size; (void)ws_size;
  const float* x     = (const float*)d_in[0];
  const float* Wqkv  = (const float*)d_in[1];
  const float* bqkv  = (const float*)d_in[2];
  const float* Wproj = (const float*)d_in[3];
  const float* bproj = (const float*)d_in[4];
  float* outF = (float*)d_out;

  const size_t NTOK = (size_t)B_ * T_;
  const size_t NELM = NTOK * D_;

  char* p = (char*)d_ws;
  bf16* xb     = (bf16*)p; p += NELM * 2;
  bf16* wqkvT  = (bf16*)p; p += (size_t)3 * D_ * D_ * 2;
  bf16* wprojT = (bf16*)p; p += (size_t)D_ * D_ * 2;
  bf16* qbuf   = (bf16*)p; p += NELM * 2;                 // [B*H][T][DH]  (q pre-scaled)
  bf16* kbuf   = (bf16*)p; p += NELM * 2;                 // [B*H][T][DH]
  bf16* vtbuf  = (bf16*)p; p += NELM * 2;                 // [B*H][DH][T]
  bf16* ybuf   = (bf16*)p; p += NELM * 2;                 // [B][T][D]
  float2* cs   = (float2*)p; p += (size_t)T_ * 32 * sizeof(float2);

  k_prep<<<dim3(NB_CONV + NB_TQ + NB_TP + NB_ROPE), dim3(256), 0, stream>>>(
      x, xb, Wqkv, wqkvT, Wproj, wprojT, cs);

  gemm_bt<0, 128, 192><<<dim3(512), dim3(256), 0, stream>>>(
      xb, wqkvT, bqkv, nullptr, qbuf, kbuf, vtbuf, cs, (int)NTOK, 3 * D_, D_);

  attn_fwd<<<dim3(512), dim3(256), 0, stream>>>(qbuf, kbuf, vtbuf, ybuf);

  gemm_bt<1, 64, 128><<<dim3(512), dim3(256), 0, stream>>>(
      ybuf, wprojT, bproj, outF, nullptr, nullptr, nullptr, cs, (int)NTOK, D_, D_);
}

// Round 24
// 106.210 us; speedup vs baseline: 1.3253x; 1.0367x over previous
//
#include <hip/hip_runtime.h>
#include <hip/hip_bf16.h>

#define B_ 2
#define T_ 2048
#define H_ 16
#define DH_ 64
#define D_ 1024
#define KVB 128

typedef __hip_bfloat16 bf16;
typedef __attribute__((ext_vector_type(4))) float f32x4;
typedef __attribute__((ext_vector_type(8))) short s16x8;
typedef __attribute__((ext_vector_type(4))) short s16x4;
typedef __attribute__((ext_vector_type(4))) unsigned short u16x4;
typedef __attribute__((ext_vector_type(2))) unsigned int u32x2;

__device__ __forceinline__ unsigned short f2bf_bits(float f) {
  bf16 h = __float2bfloat16(f);
  return *reinterpret_cast<unsigned short*>(&h);
}

// pack two f32 -> two truncated bf16 in one v_perm_b32 (lo -> low16, hi -> high16)
__device__ __forceinline__ unsigned pk_trunc(float lo, float hi) {
  return __builtin_amdgcn_perm(__float_as_uint(hi), __float_as_uint(lo), 0x07060302u);
}

// Schraudolph fast exp2: bitcast(int(x*2^23 + (127-sigma)*2^23)), sigma~0.0437.
// Valid for x in (-126.9, 120); rel err <= ~3%, deterministic in frac(x) so it
// cancels in softmax ratios. 1 fma + 1 cvt (4 cyc) vs v_exp_f32 TRANS (8 cyc).
__device__ __forceinline__ float fexp2(float x) {
  float t = __builtin_fmaf(x, 8388608.0f, 1064986316.0f);
  return __int_as_float((int)t);
}

__device__ __forceinline__ void gload_lds16(const bf16* g, bf16* l) {
  __builtin_amdgcn_global_load_lds(
      (const __attribute__((address_space(1))) void*)g,
      (__attribute__((address_space(3))) void*)l, 16, 0, 0);
}

// ---------------- fused prep kernel ----------------
#define NB_CONV 4096
#define NB_TQ   3072
#define NB_TP   1024
#define NB_ROPE 256

__global__ __launch_bounds__(256)
void k_prep(const float* __restrict__ x, bf16* __restrict__ xb,
            const float* __restrict__ Wqkv, bf16* __restrict__ wqkvT,
            const float* __restrict__ Wproj, bf16* __restrict__ wprojT,
            float2* __restrict__ cs) {
  __shared__ float t[32][33];
  const int tid = threadIdx.x;
  int bid = blockIdx.x;
  if (bid < NB_CONV) {
    const int i = bid * 256 + tid;
    float4 v = reinterpret_cast<const float4*>(x)[i];
    u16x4 o;
    o[0] = f2bf_bits(v.x); o[1] = f2bf_bits(v.y);
    o[2] = f2bf_bits(v.z); o[3] = f2bf_bits(v.w);
    reinterpret_cast<u16x4*>(xb)[i] = o;
    return;
  }
  bid -= NB_CONV;
  if (bid < NB_TQ + NB_TP) {
    const float* in;
    bf16* out;
    int R, C, bx, by;
    if (bid < NB_TQ) { in = Wqkv; out = wqkvT; R = 1024; C = 3072; bx = bid % 96; by = bid / 96; }
    else { int tt = bid - NB_TQ; in = Wproj; out = wprojT; R = 1024; C = 1024; bx = tt & 31; by = tt >> 5; }
    const int c0 = bx * 32, r0 = by * 32;
    // vectorized 32x32 transpose: 1 float4 load + 1 8B bf16 store per thread
    const int row = tid >> 3, col4 = (tid & 7) * 4;
    float4 v = *reinterpret_cast<const float4*>(&in[(size_t)(r0 + row) * C + (c0 + col4)]);
    t[row][col4 + 0] = v.x; t[row][col4 + 1] = v.y;
    t[row][col4 + 2] = v.z; t[row][col4 + 3] = v.w;
    __syncthreads();
    u16x4 o;
    o[0] = f2bf_bits(t[col4 + 0][row]);
    o[1] = f2bf_bits(t[col4 + 1][row]);
    o[2] = f2bf_bits(t[col4 + 2][row]);
    o[3] = f2bf_bits(t[col4 + 3][row]);
    *reinterpret_cast<u16x4*>(&out[(size_t)(c0 + row) * R + (r0 + col4)]) = o;
    return;
  }
  bid -= NB_TQ + NB_TP;
  {
    const int i = bid * 256 + tid;
    const int tt = i >> 5, f = i & 31;
    const float NEG_L2_BASE_OVER_32 = -0.41524101186092f;  // -log2(10000)/32
    float inv = exp2f((float)f * NEG_L2_BASE_OVER_32);
    float a = (float)tt * inv;
    cs[i] = make_float2(__cosf(a), __sinf(a));
  }
}

// ---------------- GEMM: C = A[M][K] * (Bt[N][K])^T + bias ----------------
// BK=64 single-barrier dbuf + LDS slot swizzle (r15) + BM/BN templated (r16/r22).
// r23: fragment ds_reads issued BEFORE the stage burst (globals slide into MFMA shadow).
template <int EPI, int BM, int BN>
__global__ __launch_bounds__(256, 2)
void gemm_bt(const bf16* __restrict__ A, const bf16* __restrict__ Bt,
             const float* __restrict__ bias, float* __restrict__ outF,
             bf16* __restrict__ qb, bf16* __restrict__ kb, bf16* __restrict__ vb,
             const float2* __restrict__ cs, int M, int N, int K) {
  constexpr int MI = BM / 32;
  constexpr int NJ = BN / 32;
  constexpr int WM = BM / 2;
  constexpr int WN = BN / 2;
  __shared__ __align__(16) bf16 As[2][BM * 64];
  __shared__ __align__(16) bf16 Bs[2][BN * 64];
  const int tid = threadIdx.x;
  const int w = tid >> 6, l = tid & 63;
  const int wr = w >> 1, wc = w & 1;
  const int nwg = gridDim.x;
  int bid = blockIdx.x;
  bid = (bid & 7) * (nwg >> 3) + (bid >> 3);
  const int nxb = N / BN;
  const int m0 = (bid / nxb) * BM, n0 = (bid % nxb) * BN;
  const int l15 = l & 15, l4 = l >> 4;
  const int srow = w * 8 + (l >> 3);
  const int sslot = (l & 7) ^ ((l >> 3) & 7);
  const int rsw = l15 & 7;
  f32x4 acc[MI][NJ] = {};

  auto stage = [&](int k0, int b) {
    #pragma unroll
    for (int p = 0; p < BM / 32; ++p) {
      const int row = p * 32 + srow;
      gload_lds16(A + (size_t)(m0 + row) * K + k0 + sslot * 8, &As[b][(p * 32 + w * 8) * 64] + l * 8);
    }
    #pragma unroll
    for (int p = 0; p < BN / 32; ++p) {
      const int row = p * 32 + srow;
      gload_lds16(Bt + (size_t)(n0 + row) * K + k0 + sslot * 8, &Bs[b][(p * 32 + w * 8) * 64] + l * 8);
    }
  };

  const int nt = K >> 6;
  stage(0, 0);
  __syncthreads();
  int bufi = 0;
  for (int t = 0; t < nt; ++t) {
    s16x8 af[MI][2], bfr[NJ][2];
    #pragma unroll
    for (int i = 0; i < MI; ++i)
      #pragma unroll
      for (int h = 0; h < 2; ++h)
        af[i][h] = *(const s16x8*)(&As[bufi][(wr * WM + i * 16 + l15) * 64] + (((h * 4 + l4) ^ rsw) * 8));
    #pragma unroll
    for (int j = 0; j < NJ; ++j)
      #pragma unroll
      for (int h = 0; h < 2; ++h)
        bfr[j][h] = *(const s16x8*)(&Bs[bufi][(wc * WN + j * 16 + l15) * 64] + (((h * 4 + l4) ^ rsw) * 8));
    if (t + 1 < nt) stage((t + 1) << 6, bufi ^ 1);
    #pragma unroll
    for (int i = 0; i < MI; ++i)
      #pragma unroll
      for (int j = 0; j < NJ; ++j) {
        acc[i][j] = __builtin_amdgcn_mfma_f32_16x16x32_bf16(af[i][0], bfr[j][0], acc[i][j], 0, 0, 0);
        acc[i][j] = __builtin_amdgcn_mfma_f32_16x16x32_bf16(af[i][1], bfr[j][1], acc[i][j], 0, 0, 0);
      }
    __syncthreads();
    bufi ^= 1;
  }

  if (EPI == 1) {
    #pragma unroll
    for (int i = 0; i < MI; ++i)
      #pragma unroll
      for (int j = 0; j < NJ; ++j) {
        const int ng = n0 + wc * WN + j * 16 + l15;
        const float bv = bias[ng];
        #pragma unroll
        for (int jj = 0; jj < 4; ++jj) {
          const int mg = m0 + wr * WM + i * 16 + l4 * 4 + jj;
          outF[(size_t)mg * N + ng] = acc[i][j][jj] + bv;
        }
      }
  } else {
    const float SCL2 = 0.125f * 1.44269504089f;
    #pragma unroll
    for (int i = 0; i < MI; ++i)
      #pragma unroll
      for (int j = 0; j < NJ; ++j) {
        const int ng = n0 + wc * WN + j * 16 + l15;
        const int part = ng >> 10;
        const int d = ng & 63;
        const int h = (ng >> 6) & 15;
        const float bv = bias[ng];
        if (part == 2) {
          const int mg0 = m0 + wr * WM + i * 16 + l4 * 4;
          const int t0 = mg0 & (T_ - 1);
          const int b = mg0 >> 11;
          u16x4 ov;
          #pragma unroll
          for (int jj = 0; jj < 4; ++jj) ov[jj] = f2bf_bits(acc[i][j][jj] + bv);
          *(u16x4*)(vb + ((size_t)(b * H_ + h) * DH_ + d) * T_ + t0) = ov;
        } else {
          #pragma unroll
          for (int jj = 0; jj < 4; ++jj) {
            const int mg = m0 + wr * WM + i * 16 + l4 * 4 + jj;
            const int t = mg & (T_ - 1);
            const int b = mg >> 11;
            float v = acc[i][j][jj] + bv;
            float pp = __shfl_xor(v, 1);
            float2 csv = cs[t * 32 + (d >> 1)];
            float o = (d & 1) ? (v * csv.x + pp * csv.y) : (v * csv.x - pp * csv.y);
            if (part == 0) o *= SCL2;
            bf16* dst = (part == 0) ? qb : kb;
            dst[(size_t)((b * H_ + h) * T_ + t) * DH_ + d] = __float2bfloat16(o);
          }
        }
      }
  }
}

// ---------------- flash attention v8d: r23 + Schraudolph exp2 ----------------
// exp2(s) -> fma+cvt bit-trick (TRANS 8cyc -> VALU 4cyc per score). Mask value
// -126.0f keeps the conversion in-range (P ~ 2^-126 ~= 0).
__global__ __launch_bounds__(256, 2)
void attn_fwd(const bf16* __restrict__ qb, const bf16* __restrict__ kb,
              const bf16* __restrict__ vtb, bf16* __restrict__ y) {
  __shared__ __align__(16) bf16 Ks[2][KVB * 64];   // 32 KB
  __shared__ __align__(16) bf16 Vs[2][64 * KVB];   // 32 KB

  const int tid = threadIdx.x;
  const int w = tid >> 6, l = tid & 63;
  const int l15 = l & 15, l4 = l >> 4;
  // XCD-grouped mapping (r21 WIN: FETCH 63.6->12.4 MB)
  const int xcd = blockIdx.x & 7;
  const int slot = blockIdx.x >> 3;
  const int bh = xcd * 4 + (slot & 3);
  const int pi = slot >> 2;
  const int nkt = (33 - pi) >> 1;
  const int wqA = pi * 64 + w * 16;
  const int wqB = (31 - pi) * 64 + w * 16;

  const bf16* qp = qb + (size_t)bh * T_ * DH_;
  const bf16* kp = kb + (size_t)bh * T_ * DH_;
  const bf16* vtp = vtb + (size_t)bh * DH_ * T_;

  const s16x8 qA0 = *(const s16x8*)(qp + (size_t)(wqA + l15) * DH_ + l4 * 8);
  const s16x8 qA1 = *(const s16x8*)(qp + (size_t)(wqA + l15) * DH_ + l4 * 8 + 32);
  const s16x8 qB0 = *(const s16x8*)(qp + (size_t)(wqB + l15) * DH_ + l4 * 8);
  const s16x8 qB1 = *(const s16x8*)(qp + (size_t)(wqB + l15) * DH_ + l4 * 8 + 32);

  const int krow_ = tid >> 3, kslot_ = tid & 7;
  const int vrow_ = tid >> 4, vslot_ = tid & 15;

  auto stage = [&](int kt, int b) {
    const bf16* ksrc = kp + (size_t)kt * KVB * DH_;
    #pragma unroll
    for (int p = 0; p < 4; ++p) {
      const int r = p * 32 + krow_;
      gload_lds16(ksrc + (size_t)r * DH_ + ((kslot_ ^ (r & 7)) * 8),
                  &Ks[b][r * 64 + kslot_ * 8]);
    }
    #pragma unroll
    for (int p = 0; p < 4; ++p) {
      const int r = p * 16 + vrow_;
      gload_lds16(vtp + (size_t)r * T_ + kt * KVB + ((vslot_ ^ (r & 15)) * 8),
                  &Vs[b][r * KVB + vslot_ * 8]);
    }
  };

  f32x4 OA[4] = {}, OB[4] = {};
  float lsA = 0.0f, lsB = 0.0f;   // per-lane partials; reduced once in epilogue

  stage(0, 0);
  __syncthreads();

  int buf = 0;
  for (int kt = 0; kt < nkt; ++kt) {
    const int k0 = kt * KVB;
    const bool actA = (k0 <= wqA + 15);

    f32x4 sA[8], sB[8];
    const int rsw = l15 & 7;
    __builtin_amdgcn_s_setprio(1);
    #pragma unroll
    for (int ks = 0; ks < 8; ++ks) {
      const bf16* krow = &Ks[buf][(ks * 16 + l15) * 64];
      const s16x8 kf0 = *(const s16x8*)(krow + ((l4 ^ rsw) * 8));
      const s16x8 kf1 = *(const s16x8*)(krow + (((4 + l4) ^ rsw) * 8));
      f32x4 t = {};
      t = __builtin_amdgcn_mfma_f32_16x16x32_bf16(kf0, qB0, t, 0, 0, 0);
      t = __builtin_amdgcn_mfma_f32_16x16x32_bf16(kf1, qB1, t, 0, 0, 0);
      sB[ks] = t;
      if (actA) {
        f32x4 u = {};
        u = __builtin_amdgcn_mfma_f32_16x16x32_bf16(kf0, qA0, u, 0, 0, 0);
        u = __builtin_amdgcn_mfma_f32_16x16x32_bf16(kf1, qA1, u, 0, 0, 0);
        sA[ks] = u;
      }
    }
    __builtin_amdgcn_s_setprio(0);

    if (kt + 1 < nkt) stage(kt + 1, buf ^ 1);   // issues under softmax + PV

    auto softmax = [&](f32x4 (&s)[8], float& lsum, int wq) {
      if (k0 + KVB - 1 > wq) {
        const int q = wq + l15;
        #pragma unroll
        for (int ks = 0; ks < 8; ++ks)
          #pragma unroll
          for (int j = 0; j < 4; ++j)
            if (k0 + ks * 16 + l4 * 4 + j > q) s[ks][j] = -126.0f;  // fexp2-safe mask
      }
      float ts = 0.0f;
      #pragma unroll
      for (int ks = 0; ks < 8; ++ks) {
        f32x4 pv;
        #pragma unroll
        for (int j = 0; j < 4; ++j) pv[j] = fexp2(s[ks][j]);   // scale pre-folded into q
        s[ks] = pv;
        ts += (pv[0] + pv[1]) + (pv[2] + pv[3]);
      }
      lsum += ts;   // per-lane partial; cross-lane reduce deferred to epilogue
    };
    softmax(sB, lsB, wqB);
    if (actA) softmax(sA, lsA, wqA);

    __builtin_amdgcn_s_setprio(1);
    #pragma unroll
    for (int ks = 0; ks < 8; ++ks) {
      s16x4 pbB = {}, pbA = {};
      {
        u32x2 t2;
        t2.x = pk_trunc(sB[ks][0], sB[ks][1]);
        t2.y = pk_trunc(sB[ks][2], sB[ks][3]);
        pbB = __builtin_bit_cast(s16x4, t2);
      }
      if (actA) {
        u32x2 t2;
        t2.x = pk_trunc(sA[ks][0], sA[ks][1]);
        t2.y = pk_trunc(sA[ks][2], sA[ks][3]);
        pbA = __builtin_bit_cast(s16x4, t2);
      }
      const int slotb = ks * 2 + (l4 >> 1);
      const int inoff = (l4 & 1) * 8;
      #pragma unroll
      for (int dt = 0; dt < 4; ++dt) {
        const int d = dt * 16 + l15;
        const char* vrow = (const char*)&Vs[buf][d * KVB];
        u16x4 vf = *(const u16x4*)(vrow + ((slotb ^ (d & 15)) * 16 + inoff));
        OB[dt] = __builtin_amdgcn_mfma_f32_16x16x16bf16_1k(*(const s16x4*)&vf, pbB, OB[dt], 0, 0, 0);
        if (actA)
          OA[dt] = __builtin_amdgcn_mfma_f32_16x16x16bf16_1k(*(const s16x4*)&vf, pbA, OA[dt], 0, 0, 0);
      }
    }
    __builtin_amdgcn_s_setprio(0);

    __syncthreads();   // single barrier: stage(kt+1) landed; all reads of buf done
    buf ^= 1;
  }

  // one cross-lane reduce for the whole kernel (lanes {q, q+16, q+32, q+48})
  lsB += __shfl_xor(lsB, 16); lsB += __shfl_xor(lsB, 32);
  lsA += __shfl_xor(lsA, 16); lsA += __shfl_xor(lsA, 32);

  const int b = bh >> 4, h = bh & 15;
  auto writeO = [&](f32x4 (&O)[4], float lsum, int wq) {
    const float inv = 1.0f / lsum;
    bf16* yr = y + ((size_t)(b * T_ + wq + l15)) * D_ + h * DH_;
    #pragma unroll
    for (int dt = 0; dt < 4; ++dt) {
      u32x2 ov;
      ov.x = pk_trunc(O[dt][0] * inv, O[dt][1] * inv);
      ov.y = pk_trunc(O[dt][2] * inv, O[dt][3] * inv);
      *(u32x2*)(yr + dt * 16 + l4 * 4) = ov;
    }
  };
  writeO(OA, lsA, wqA);
  writeO(OB, lsB, wqB);
}

// ---------------- launcher ----------------

extern "C" void kernel_launch(void* const* d_in, const int* in_sizes, int n_in,
                              void* d_out, int out_size, void* d_ws, size_t ws_size,
                              hipStream_t stream) {
  (void)in_sizes; (void)n_in; (void)out_size; (void)ws_size;
  const float* x     = (const float*)d_in[0];
  const float* Wqkv  = (const float*)d_in[1];
  const float* bqkv  = (const float*)d_in[2];
  const float* Wproj = (const float*)d_in[3];
  const float* bproj = (const float*)d_in[4];
  float* outF = (float*)d_out;

  const size_t NTOK = (size_t)B_ * T_;
  const size_t NELM = NTOK * D_;

  char* p = (char*)d_ws;
  bf16* xb     = (bf16*)p; p += NELM * 2;
  bf16* wqkvT  = (bf16*)p; p += (size_t)3 * D_ * D_ * 2;
  bf16* wprojT = (bf16*)p; p += (size_t)D_ * D_ * 2;
  bf16* qbuf   = (bf16*)p; p += NELM * 2;                 // [B*H][T][DH]  (q pre-scaled)
  bf16* kbuf   = (bf16*)p; p += NELM * 2;                 // [B*H][T][DH]
  bf16* vtbuf  = (bf16*)p; p += NELM * 2;                 // [B*H][DH][T]
  bf16* ybuf   = (bf16*)p; p += NELM * 2;                 // [B][T][D]
  float2* cs   = (float2*)p; p += (size_t)T_ * 32 * sizeof(float2);

  k_prep<<<dim3(NB_CONV + NB_TQ + NB_TP + NB_ROPE), dim3(256), 0, stream>>>(
      x, xb, Wqkv, wqkvT, Wproj, wprojT, cs);

  gemm_bt<0, 128, 192><<<dim3(512), dim3(256), 0, stream>>>(
      xb, wqkvT, bqkv, nullptr, qbuf, kbuf, vtbuf, cs, (int)NTOK, 3 * D_, D_);

  attn_fwd<<<dim3(512), dim3(256), 0, stream>>>(qbuf, kbuf, vtbuf, ybuf);

  gemm_bt<1, 64, 128><<<dim3(512), dim3(256), 0, stream>>>(
      ybuf, wprojT, bproj, outF, nullptr, nullptr, nullptr, cs, (int)NTOK, D_, D_);
}